// Round 11
// baseline (334.752 us; speedup 1.0000x reference)
//
#include <hip/hip_runtime.h>
#include <hip/hip_bf16.h>

// ---- problem constants ----
#define SEQLEN   1024
#define NTOK     2048          // BATCH * SEQLEN
#define DMODEL   1024
#define DSTATE   128
#define DINNER   2048
#define NHEADS   32
#define HEADDIM  64
#define CONVDIM  2304          // DINNER + 2*DSTATE
#define DINPROJ  4384          // 2*DINNER + 2*DSTATE + NHEADS
#define INTER    2752
#define Q        64            // scan chunk length
#define NCHUNK   16            // SEQLEN / Q

typedef __hip_bfloat16 bf16;
typedef unsigned short ushort_t;
typedef __attribute__((ext_vector_type(8))) short bf16x8;
typedef __attribute__((ext_vector_type(4))) float f32x4;
typedef __attribute__((ext_vector_type(4))) unsigned short u16x4;

__device__ __forceinline__ float bf2f(bf16 x) { return __bfloat162float(x); }
__device__ __forceinline__ float bfu2f(ushort_t u) {
    return __uint_as_float(((unsigned)u) << 16);
}
__device__ __forceinline__ ushort_t f2bfu(float x) {
    union { bf16 h; ushort_t u; } c; c.h = __float2bfloat16(x); return c.u;
}

__device__ __forceinline__ void glds16(const void* g, void* l) {
    __builtin_amdgcn_global_load_lds(
        (const __attribute__((address_space(1))) void*)g,
        (__attribute__((address_space(3))) void*)l, 16, 0, 0);
}

// counted-vmcnt pipeline fence (T3+T4) for the fat-tile GEMM.
template <int N>
__device__ __forceinline__ void pipe_fence() {
    if constexpr (N == 4)
        asm volatile("s_waitcnt vmcnt(4) lgkmcnt(0)" ::: "memory");
    else if constexpr (N == 2)
        asm volatile("s_waitcnt vmcnt(2) lgkmcnt(0)" ::: "memory");
    else
        asm volatile("s_waitcnt vmcnt(0) lgkmcnt(0)" ::: "memory");
    __builtin_amdgcn_s_barrier();
    __builtin_amdgcn_sched_barrier(0);
}

__device__ inline float block_reduce_sum(float v) {
    __shared__ float red[4];
    #pragma unroll
    for (int off = 32; off >= 1; off >>= 1) v += __shfl_down(v, off);
    int lane = threadIdx.x & 63, w = threadIdx.x >> 6;
    if (lane == 0) red[w] = v;
    __syncthreads();
    return red[0] + red[1] + red[2] + red[3];
}

// ---- fused: rmsnorm(hidden) -> h_norm  (blocks [0,2048))
//      + fp32->bf16 in_proj weight convert (blocks [2048, 2048+4384)) ----
__global__ __launch_bounds__(256) void prep_kernel(
    const float* __restrict__ hidden, const float* __restrict__ norm_w,
    bf16* __restrict__ h_norm,
    const float* __restrict__ wsrc, ushort_t* __restrict__ wdst)
{
    const int bid = blockIdx.x, t = threadIdx.x;
    if (bid < NTOK) {
        const int token = bid;
        float v[4]; float ss = 0.f;
        #pragma unroll
        for (int i = 0; i < 4; i++) {
            v[i] = hidden[(size_t)token * DMODEL + t * 4 + i];
            ss += v[i] * v[i];
        }
        ss = block_reduce_sum(ss);
        const float scale = rsqrtf(ss * (1.0f / DMODEL) + 1e-6f);
        #pragma unroll
        for (int i = 0; i < 4; i++)
            h_norm[(size_t)token * DMODEL + t * 4 + i] =
                __float2bfloat16(v[i] * scale * norm_w[t * 4 + i]);
    } else {
        const int i = ((bid - NTOK) * 256 + t) * 4;
        if (i < DINPROJ * DMODEL) {
            const f32x4 v = *(const f32x4*)(wsrc + i);
            u16x4 o;
            #pragma unroll
            for (int k = 0; k < 4; k++) o[k] = f2bfu(v[k]);
            *(u16x4*)(wdst + i) = o;
        }
    }
}

// ---- fused convert of out_proj / gate(interleave even) / up(odd) / down ----
#define NWOP (DMODEL * DINNER)     // 2,097,152
#define NWG  (INTER * DMODEL)      // 2,818,048
__global__ __launch_bounds__(256) void convert_weights_kernel(
    const float* __restrict__ wop, const float* __restrict__ wg,
    const float* __restrict__ wu, const float* __restrict__ wd,
    ushort_t* __restrict__ dWop, ushort_t* __restrict__ dWgu,
    ushort_t* __restrict__ dWdn)
{
    const int i4 = (blockIdx.x * 256 + threadIdx.x) * 4;
    const float* src;
    ushort_t* dst;
    if (i4 < NWOP) { src = wop + i4; dst = dWop + i4; }
    else if (i4 < NWOP + NWG) {
        const int e = i4 - NWOP, row = e >> 10, col = e & 1023;
        src = wg + e; dst = dWgu + ((size_t)(2 * row) << 10) + col;
    } else if (i4 < NWOP + 2 * NWG) {
        const int e = i4 - NWOP - NWG, row = e >> 10, col = e & 1023;
        src = wu + e; dst = dWgu + ((size_t)(2 * row + 1) << 10) + col;
    } else if (i4 < NWOP + 3 * NWG) {
        const int e = i4 - NWOP - 2 * NWG;
        src = wd + e; dst = dWdn + e;
    } else return;
    const f32x4 v = *(const f32x4*)src;
    u16x4 o;
    #pragma unroll
    for (int k = 0; k < 4; k++) o[k] = f2bfu(v[k]);
    *(u16x4*)dst = o;
}

// ---- RMSNorm over 1024 dims (fp32 in, fp32 weights) -> bf16 out ----
__global__ __launch_bounds__(256) void rmsnorm1024_kernel(
    const float* __restrict__ x, const float* __restrict__ w, bf16* __restrict__ out)
{
    const int token = blockIdx.x, t = threadIdx.x;
    float v[4]; float ss = 0.f;
    #pragma unroll
    for (int i = 0; i < 4; i++) {
        v[i] = x[(size_t)token * DMODEL + t * 4 + i];
        ss += v[i] * v[i];
    }
    ss = block_reduce_sum(ss);
    const float scale = rsqrtf(ss * (1.0f / DMODEL) + 1e-6f);
    #pragma unroll
    for (int i = 0; i < 4; i++)
        out[(size_t)token * DMODEL + t * 4 + i] =
            __float2bfloat16(v[i] * scale * w[t * 4 + i]);
}

// ---- FAT GEMM: MT x NT, BK=32, 3-buffer 2-deep counted-vmcnt + setprio ----
// LDS [row][4 chunks of 8 ushorts]; stored chunk = src ^ ((row>>1)&3);
// read chunk = fq ^ ((fr>>1)&3) -> conflict-free (both-sides swizzle).
// EPI 2: swiglu -> out_bf (interleaved W)
// EPI 3: in_proj split output: z f32 / xBC bf16 / dt_raw f32
template <int EPI, int MT, int NT>
__global__ __launch_bounds__(256) void gemm_bf(
    const bf16* __restrict__ A, const bf16* __restrict__ W,
    float* __restrict__ Cf, float* __restrict__ aux_f,
    bf16* __restrict__ out_bf, int M, int N, int K)
{
    __shared__ ushort_t As[3][MT * 32];
    __shared__ ushort_t Bs[3][NT * 32];
    const int tid = threadIdx.x;
    const int w = tid >> 6, lane = tid & 63;
    constexpr int NLD = MT / 64 + NT / 64;   // glds instrs per wave per K-tile

    // XCD swizzle (bijective; m-major within each XCD chunk)
    const int gdx = gridDim.x, gdy = gridDim.y;
    const int nwg = gdx * gdy;
    const int orig = blockIdx.x + gdx * blockIdx.y;
    const int q8 = nwg >> 3, r8 = nwg & 7;
    const int xcd = orig & 7, lin = orig >> 3;
    const int wg = (xcd < r8 ? xcd * (q8 + 1) : r8 * (q8 + 1) + (xcd - r8) * q8) + lin;
    const int m0 = (wg % gdy) * MT;
    const int n0 = (wg / gdy) * NT;

    const int srow = tid >> 2;                               // 0..63
    const int scol = (((tid & 3) ^ ((srow >> 1) & 3)) * 8);  // swizzled src col
    const bf16* Agp[MT / 64];
    const bf16* Wgp[NT / 64];
    #pragma unroll
    for (int i = 0; i < MT / 64; i++)
        Agp[i] = A + (size_t)(m0 + i * 64 + srow) * K + scol;
    #pragma unroll
    for (int i = 0; i < NT / 64; i++) {
        const int nr = n0 + i * 64 + srow;
        Wgp[i] = W + (size_t)(nr < N ? nr : 0) * K + scol;
    }

    const int wy = w >> 1, wx = w & 1;
    const int fr = lane & 15;
    const int fq = lane >> 4;            // k-chunk (x8 ushorts) within K=32
    const int cxor = (fr >> 1) & 3;      // read-side swizzle (row-derived)
    constexpr int MI = MT / 32;
    constexpr int NJ = NT / 32;
    f32x4 acc[MI][NJ];
    #pragma unroll
    for (int i = 0; i < MI; i++)
        #pragma unroll
        for (int j = 0; j < NJ; j++)
            acc[i][j] = (f32x4){0.f, 0.f, 0.f, 0.f};

    const int nk = K >> 5;

    #define STAGE(buf, koff) do {                                         \
        ushort_t* sa_ = &As[buf][w * 512];                                \
        ushort_t* sb_ = &Bs[buf][w * 512];                                \
        _Pragma("unroll")                                                 \
        for (int i_ = 0; i_ < MT / 64; i_++)                              \
            glds16(Agp[i_] + (koff), sa_ + i_ * 2048);                    \
        _Pragma("unroll")                                                 \
        for (int i_ = 0; i_ < NT / 64; i_++)                              \
            glds16(Wgp[i_] + (koff), sb_ + i_ * 2048);                    \
    } while (0)

    STAGE(0, 0);
    STAGE(1, 32);
    pipe_fence<NLD>();

    int cur = 0, stg = 2;
    for (int kt = 0; kt < nk; ++kt) {
        const bool pf = (kt + 2 < nk);
        if (pf) STAGE(stg, (kt + 2) << 5);
        const ushort_t* ca = As[cur];
        const ushort_t* cb = Bs[cur];
        bf16x8 af[MI], bfv[NJ];
        #pragma unroll
        for (int i = 0; i < MI; i++) {
            const int r = wy * (MT / 2) + i * 16 + fr;
            af[i] = *(const bf16x8*)&ca[r * 32 + ((fq ^ cxor) * 8)];
        }
        #pragma unroll
        for (int j = 0; j < NJ; j++) {
            const int r = wx * (NT / 2) + j * 16 + fr;
            bfv[j] = *(const bf16x8*)&cb[r * 32 + ((fq ^ cxor) * 8)];
        }
        __builtin_amdgcn_s_setprio(1);   // T5: favor MFMA vs other blocks' staging
        #pragma unroll
        for (int i = 0; i < MI; i++)
            #pragma unroll
            for (int j = 0; j < NJ; j++)
                acc[i][j] = __builtin_amdgcn_mfma_f32_16x16x32_bf16(
                    af[i], bfv[j], acc[i][j], 0, 0, 0);
        __builtin_amdgcn_s_setprio(0);
        if (pf)               pipe_fence<NLD>();
        else if (kt + 1 < nk) pipe_fence<0>();
        cur = (cur == 2) ? 0 : cur + 1;
        stg = (stg == 2) ? 0 : stg + 1;
    }
    #undef STAGE

    // C/D layout: col = lane&15, row = (lane>>4)*4 + reg
    #pragma unroll
    for (int i = 0; i < MI; i++) {
        #pragma unroll
        for (int j = 0; j < NJ; j++) {
            const int mb = m0 + wy * (MT / 2) + i * 16 + (lane >> 4) * 4;
            const int nn = n0 + wx * (NT / 2) + j * 16 + (lane & 15);
            if (nn < N) {
                #pragma unroll
                for (int r = 0; r < 4; r++) {
                    if (EPI == 2) {
                        const float g = acc[i][j][r];
                        const float u = __shfl_xor(g, 1);
                        if (!(lane & 1)) {
                            const float a = (g / (1.f + expf(-g))) * u;
                            out_bf[(size_t)(mb + r) * (N / 2) + (nn >> 1)] =
                                __float2bfloat16(a);
                        }
                    } else {   // EPI == 3: split in_proj output
                        const float v = acc[i][j][r];
                        if (n0 < DINNER) {
                            Cf[(size_t)(mb + r) * DINNER + nn] = v;
                        } else if (n0 < DINNER + CONVDIM) {
                            out_bf[(size_t)(mb + r) * CONVDIM + (nn - DINNER)] =
                                __float2bfloat16(v);
                        } else {
                            aux_f[(size_t)(mb + r) * NHEADS +
                                  (nn - (DINNER + CONVDIM))] = v;
                        }
                    }
                }
            }
        }
    }
}

// ---- SMALL GEMM: 64x64 tile, NKT x 64 K-cols per barrier pair, 2-buf.
// NKT=2 for K=2048; NKT=1 for K=2752. Cf = acc + resid.
template <int NKT>
__global__ __launch_bounds__(256) void gemm_bf_s(
    const bf16* __restrict__ A, const bf16* __restrict__ W,
    float* __restrict__ Cf, const float* __restrict__ resid_f,
    int M, int N, int K)
{
    constexpr int MT = 64, NT = 64;
    __shared__ ushort_t As[2][MT * 64 * NKT];
    __shared__ ushort_t Bs[2][NT * 64 * NKT];
    const int tid = threadIdx.x;
    const int w = tid >> 6, lane = tid & 63;

    const int gdx = gridDim.x, gdy = gridDim.y;
    const int nwg = gdx * gdy;
    const int orig = blockIdx.x + gdx * blockIdx.y;
    const int q8 = nwg >> 3, r8 = nwg & 7;
    const int xcd = orig & 7, lin = orig >> 3;
    const int wg = (xcd < r8 ? xcd * (q8 + 1) : r8 * (q8 + 1) + (xcd - r8) * q8) + lin;
    const int m0 = (wg % gdy) * MT;
    const int n0 = (wg / gdy) * NT;

    const int srow = tid >> 3;                               // 0..31
    const int scol = (((tid & 7) ^ (srow & 7)) * 8);
    const bf16* Agp[2];
    const bf16* Wgp[2];
    #pragma unroll
    for (int i = 0; i < 2; i++)
        Agp[i] = A + (size_t)(m0 + i * 32 + srow) * K + scol;
    #pragma unroll
    for (int i = 0; i < 2; i++) {
        const int nr = n0 + i * 32 + srow;
        Wgp[i] = W + (size_t)(nr < N ? nr : 0) * K + scol;
    }

    const int wy = w >> 1, wx = w & 1;
    const int fr = lane & 15;
    const int fq = lane >> 4;
    f32x4 acc[2][2];
    #pragma unroll
    for (int i = 0; i < 2; i++)
        #pragma unroll
        for (int j = 0; j < 2; j++)
            acc[i][j] = (f32x4){0.f, 0.f, 0.f, 0.f};

    const int nk = K / (64 * NKT);

    #define STAGE_S(buf, koff) do {                                       \
        _Pragma("unroll")                                                 \
        for (int s_ = 0; s_ < NKT; s_++) {                                \
            _Pragma("unroll")                                             \
            for (int i_ = 0; i_ < 2; i_++) {                              \
                glds16(Agp[i_] + (koff) + s_ * 64,                        \
                       &As[buf][s_ * 4096 + i_ * 2048 + w * 512]);        \
                glds16(Wgp[i_] + (koff) + s_ * 64,                        \
                       &Bs[buf][s_ * 4096 + i_ * 2048 + w * 512]);        \
            }                                                             \
        }                                                                 \
    } while (0)

    STAGE_S(0, 0);
    __syncthreads();

    for (int kt = 0; kt < nk; ++kt) {
        const int cur = kt & 1;
        if (kt + 1 < nk) STAGE_S(cur ^ 1, (kt + 1) * (64 * NKT));
        const ushort_t* ca = As[cur];
        const ushort_t* cb = Bs[cur];
        #pragma unroll
        for (int s = 0; s < NKT; s++) {
            #pragma unroll
            for (int ks = 0; ks < 2; ks++) {
                bf16x8 af[2], bfv[2];
                #pragma unroll
                for (int i = 0; i < 2; i++) {
                    const int r = wy * 32 + i * 16 + fr;
                    const int g = ks * 4 + fq;
                    af[i] = *(const bf16x8*)&ca[s * 4096 + r * 64 + ((g ^ (r & 7)) * 8)];
                }
                #pragma unroll
                for (int j = 0; j < 2; j++) {
                    const int r = wx * 32 + j * 16 + fr;
                    const int g = ks * 4 + fq;
                    bfv[j] = *(const bf16x8*)&cb[s * 4096 + r * 64 + ((g ^ (r & 7)) * 8)];
                }
                #pragma unroll
                for (int i = 0; i < 2; i++)
                    #pragma unroll
                    for (int j = 0; j < 2; j++)
                        acc[i][j] = __builtin_amdgcn_mfma_f32_16x16x32_bf16(
                            af[i], bfv[j], acc[i][j], 0, 0, 0);
            }
        }
        __syncthreads();
    }
    #undef STAGE_S

    #pragma unroll
    for (int i = 0; i < 2; i++) {
        #pragma unroll
        for (int j = 0; j < 2; j++) {
            const int mb = m0 + wy * 32 + i * 16 + (lane >> 4) * 4;
            const int nn = n0 + wx * 32 + j * 16 + (lane & 15);
            if (nn < N) {
                #pragma unroll
                for (int r = 0; r < 4; r++) {
                    const size_t idx = (size_t)(mb + r) * N + nn;
                    Cf[idx] = acc[i][j][r] + resid_f[idx];
                }
            }
        }
    }
}

// ---- fused: depthwise causal conv (k=4)+bias+silu (4 ch/thread, bf16 in)
//      + dt = softplus(dt_raw + dt_bias) in trailing blocks (f32 dense in) ----
#define NCONVBLK ((NTOK * CONVDIM / 4) / 256)    // 4608
__global__ __launch_bounds__(256) void conv_silu_dt_kernel(
    const ushort_t* __restrict__ xbc, const float* __restrict__ dtraw,
    const float* __restrict__ cw, const float* __restrict__ cb,
    const float* __restrict__ dtbias,
    ushort_t* __restrict__ out, float* __restrict__ dtb_out)
{
    const int bid = blockIdx.x;
    if (bid < NCONVBLK) {
        const int i = bid * 256 + threadIdx.x;       // 0 .. NTOK*CONVDIM/4
        const int cg = i % (CONVDIM / 4);
        const int token = i / (CONVDIM / 4);
        const int c0 = cg * 4;
        const int l = token & (SEQLEN - 1);
        float a[4];
        #pragma unroll
        for (int j = 0; j < 4; j++) a[j] = cb[c0 + j];
        f32x4 cwv[4];
        #pragma unroll
        for (int j = 0; j < 4; j++) cwv[j] = *(const f32x4*)(cw + (c0 + j) * 4);
        #pragma unroll
        for (int k = 0; k < 4; k++) {
            const int ls = l - 3 + k;
            if (ls >= 0) {
                const u16x4 v = *(const u16x4*)(
                    xbc + (size_t)(token - 3 + k) * CONVDIM + c0);
                #pragma unroll
                for (int j = 0; j < 4; j++) a[j] += bfu2f(v[j]) * cwv[j][k];
            }
        }
        u16x4 o;
        #pragma unroll
        for (int j = 0; j < 4; j++)
            o[j] = f2bfu(a[j] / (1.f + expf(-a[j])));
        *(u16x4*)(out + (size_t)token * CONVDIM + c0) = o;
    } else {
        const int idx = (bid - NCONVBLK) * 256 + threadIdx.x;   // NTOK*NHEADS
        const int h = idx & (NHEADS - 1);
        const float v = dtraw[idx] + dtbias[h];
        dtb_out[idx] = (v > 20.f) ? v : log1pf(expf(v));
    }
}

// ================= chunked scan =================
// Phase A (MFMA): S[p,n] = sum_l (w_l x[l,p]) B[l,n],  w_l = exp(cumQ-cum_l)*dt_l
// Staging vectorized: u16x4 global loads, transposed scalar LDS stores
// (<=2-way store conflicts; global side 4x fewer loads).
__global__ __launch_bounds__(256) void chunk_state_kernel(
    const ushort_t* __restrict__ cvb, const float* __restrict__ dtb,
    const float* __restrict__ A_log, float* __restrict__ ccum,
    ushort_t* __restrict__ Sbuf)
{
    const int bx = blockIdx.x;
    const int bh = bx >> 4, c = bx & 15;
    const int b = bh >> 5, h = bh & 31;
    const int t = threadIdx.x;
    const int w = t >> 6, lane = t & 63;
    const int wy = w >> 1, wx = w & 1;
    const int fr = lane & 15, fk = (lane >> 4) * 8, cr = (lane >> 4) * 4;
    const int tok0 = b * SEQLEN + c * Q;
    const float A = -expf(A_log[h]);

    __shared__ ushort_t sXT[64 * 88];    // [p][l], weighted
    __shared__ ushort_t sBT[128 * 88];   // [n][l]
    __shared__ float sW[64];

    if (t < 64) {
        const float d = dtb[(size_t)(tok0 + t) * NHEADS + h];
        float s = d;
        #pragma unroll
        for (int off = 1; off < 64; off <<= 1) {
            const float up = __shfl_up(s, off);
            if (t >= off) s += up;
        }
        const float total = __shfl(s, 63);
        sW[t] = expf(A * (total - s)) * d;     // arg <= 0
        if (t == 63) ccum[bh * NCHUNK + c] = A * total;
    }
    __syncthreads();

    for (int i = t; i < 64 * 16; i += 256) {
        const int l = i >> 4, p0 = (i & 15) * 4;
        const u16x4 xv = *(const u16x4*)&cvb[(size_t)(tok0 + l) * CONVDIM
                                            + h * HEADDIM + p0];
        const float wl = sW[l];
        #pragma unroll
        for (int j = 0; j < 4; j++)
            sXT[(p0 + j) * 88 + l] = f2bfu(wl * bfu2f(xv[j]));
    }
    for (int i = t; i < 128 * 16; i += 256) {
        const int l = i >> 5, n0 = (i & 31) * 4;
        const u16x4 bv = *(const u16x4*)&cvb[(size_t)(tok0 + l) * CONVDIM
                                            + DINNER + n0];
        #pragma unroll
        for (int j = 0; j < 4; j++)
            sBT[(n0 + j) * 88 + l] = bv[j];
    }
    __syncthreads();

    f32x4 acc[2][4];
    #pragma unroll
    for (int i = 0; i < 2; i++)
        #pragma unroll
        for (int j = 0; j < 4; j++)
            acc[i][j] = (f32x4){0.f, 0.f, 0.f, 0.f};
    #pragma unroll
    for (int k0 = 0; k0 < 64; k0 += 32) {
        bf16x8 af[2], bfv[4];
        #pragma unroll
        for (int i = 0; i < 2; i++)
            af[i] = *(const bf16x8*)&sXT[(wy * 32 + i * 16 + fr) * 88 + fk + k0];
        #pragma unroll
        for (int j = 0; j < 4; j++)
            bfv[j] = *(const bf16x8*)&sBT[(wx * 64 + j * 16 + fr) * 88 + fk + k0];
        #pragma unroll
        for (int i = 0; i < 2; i++)
            #pragma unroll
            for (int j = 0; j < 4; j++)
                acc[i][j] = __builtin_amdgcn_mfma_f32_16x16x32_bf16(
                    af[i], bfv[j], acc[i][j], 0, 0, 0);
    }
    const size_t slot = (size_t)(bh * NCHUNK + c) * 64 * 128;
    #pragma unroll
    for (int i = 0; i < 2; i++) {
        #pragma unroll
        for (int j = 0; j < 4; j++) {
            #pragma unroll
            for (int r = 0; r < 4; r++) {
                const int pr = wy * 32 + i * 16 + cr + r;
                const int nn = wx * 64 + j * 16 + fr;
                Sbuf[slot + pr * 128 + nn] = f2bfu(acc[i][j][r]);
            }
        }
    }
}

// Phase B: sequential stitch; writes incoming H_c into slot c.
// 8-way split over n (512 blocks, 16 cols each) for max memory-level
// parallelism; chunk c+1's load issued BEFORE chunk c's store.
__global__ __launch_bounds__(256) void stitch_kernel(
    const float* __restrict__ ccum, ushort_t* __restrict__ Sbuf)
{
    const int bh = blockIdx.x >> 3, ng = blockIdx.x & 7;
    const int t = threadIdx.x, p = t >> 2, q = t & 3;
    float P[NCHUNK];
    #pragma unroll
    for (int c = 0; c < NCHUNK; c++) P[c] = expf(ccum[bh * NCHUNK + c]);
    float H[4];
    #pragma unroll
    for (int j = 0; j < 4; j++) H[j] = 0.f;

    const size_t off0 = (size_t)p * 128 + ng * 16 + q * 4;
    #define SLOT(c) (((size_t)(bh * NCHUNK + (c)) * 64) * 128 + off0)
    u16x4 nv = *(const u16x4*)&Sbuf[SLOT(0)];
    for (int c = 0; c < NCHUNK; c++) {
        const u16x4 sv = nv;
        if (c + 1 < NCHUNK) nv = *(const u16x4*)&Sbuf[SLOT(c + 1)];
        u16x4 hv;
        #pragma unroll
        for (int k = 0; k < 4; k++) hv[k] = f2bfu(H[k]);
        *(u16x4*)&Sbuf[SLOT(c)] = hv;
        #pragma unroll
        for (int k = 0; k < 4; k++)
            H[k] = P[c] * H[k] + bfu2f(sv[k]);
    }
    #undef SLOT
}

// Phase C (MFMA): Y = mask(C@B^T)@X + (exp(cum)*C)@H^T + D*X
__global__ __launch_bounds__(256) void chunk_scan_mfma_kernel(
    const ushort_t* __restrict__ cvb, const float* __restrict__ dtb,
    const float* __restrict__ A_log, const float* __restrict__ Dh,
    const ushort_t* __restrict__ Sbuf, bf16* __restrict__ ybuf)
{
    const int bx = blockIdx.x;
    const int bh = bx >> 4, c = bx & 15;
    const int b = bh >> 5, h = bh & 31;
    const int t = threadIdx.x;
    const int w = t >> 6, lane = t & 63;
    const int wy = w >> 1, wx = w & 1;
    const int fr = lane & 15;
    const int fk = (lane >> 4) * 8;
    const int cr = (lane >> 4) * 4;
    const int tok0 = b * SEQLEN + c * Q;
    const float A = -expf(A_log[h]);
    const float Dv = Dh[h];

    __shared__ ushort_t sB[64 * 136];
    __shared__ ushort_t sC[64 * 136];
    __shared__ ushort_t sH[64 * 136];
    __shared__ ushort_t sXT[64 * 72];
    __shared__ ushort_t sM[64 * 72];
    __shared__ float    sCum[64];
    __shared__ float    sDtv[64];

    for (int i = t; i < 64 * 32; i += 256) {
        const int row = i >> 5, col = (i & 31) * 4;
        const size_t base = (size_t)(tok0 + row) * CONVDIM;
        *(u16x4*)&sB[row * 136 + col] = *(const u16x4*)&cvb[base + DINNER + col];
        *(u16x4*)&sC[row * 136 + col] = *(const u16x4*)&cvb[base + DINNER + DSTATE + col];
    }
    for (int i = t; i < 64 * 32; i += 256) {
        const int p = i >> 5, l0 = (i & 31) * 2;
        const ushort_t x0 = cvb[(size_t)(tok0 + l0)     * CONVDIM + h * HEADDIM + p];
        const ushort_t x1 = cvb[(size_t)(tok0 + l0 + 1) * CONVDIM + h * HEADDIM + p];
        *(unsigned*)&sXT[p * 72 + l0] = ((unsigned)x1 << 16) | x0;
    }
    {
        const size_t slot = (size_t)(bh * NCHUNK + c) * 64 * 128;
        for (int i = t * 4; i < 64 * 128; i += 1024) {
            const int row = i >> 7, col = i & 127;
            *(u16x4*)&sH[row * 136 + col] = *(const u16x4*)&Sbuf[slot + row * 128 + col];
        }
    }
    if (t < 64) {
        const float d = dtb[(size_t)(tok0 + t) * NHEADS + h];
        float s = d;
        #pragma unroll
        for (int off = 1; off < 64; off <<= 1) {
            const float up = __shfl_up(s, off);
            if (t >= off) s += up;
        }
        sCum[t] = A * s;
        sDtv[t] = d;
    }
    __syncthreads();

    // GEMM1: G = C @ B^T
    f32x4 accg[2][2];
    #pragma unroll
    for (int i = 0; i < 2; i++)
        #pragma unroll
        for (int j = 0; j < 2; j++)
            accg[i][j] = (f32x4){0.f, 0.f, 0.f, 0.f};
    #pragma unroll
    for (int k0 = 0; k0 < 128; k0 += 32) {
        bf16x8 af[2], bfv[2];
        #pragma unroll
        for (int i = 0; i < 2; i++)
            af[i] = *(const bf16x8*)&sC[(wy * 32 + i * 16 + fr) * 136 + fk + k0];
        #pragma unroll
        for (int j = 0; j < 2; j++)
            bfv[j] = *(const bf16x8*)&sB[(wx * 32 + j * 16 + fr) * 136 + fk + k0];
        #pragma unroll
        for (int i = 0; i < 2; i++)
            #pragma unroll
            for (int j = 0; j < 2; j++)
                accg[i][j] = __builtin_amdgcn_mfma_f32_16x16x32_bf16(
                    af[i], bfv[j], accg[i][j], 0, 0, 0);
    }
    __syncthreads();

    #pragma unroll
    for (int i = 0; i < 2; i++) {
        #pragma unroll
        for (int j = 0; j < 2; j++) {
            #pragma unroll
            for (int r = 0; r < 4; r++) {
                const int l  = wy * 32 + i * 16 + cr + r;
                const int jc = wx * 32 + j * 16 + fr;
                const float v = (jc <= l)
                    ? accg[i][j][r] * expf(sCum[l] - sCum[jc]) * sDtv[jc] : 0.f;
                sM[l * 72 + jc] = f2bfu(v);
            }
        }
    }
    for (int i = t; i < 64 * 32; i += 256) {
        const int row = i >> 5, col = (i & 31) * 4;
        const float sc = expf(sCum[row]);
        u16x4 v = *(const u16x4*)&sC[row * 136 + col];
        #pragma unroll
        for (int k = 0; k < 4; k++) v[k] = f2bfu(bfu2f(v[k]) * sc);
        *(u16x4*)&sC[row * 136 + col] = v;
    }
    __syncthreads();

    // GEMM2: Y = M @ X + (scaled C) @ H^T
    f32x4 accy[2][2];
    #pragma unroll
    for (int i = 0; i < 2; i++)
        #pragma unroll
        for (int j = 0; j < 2; j++)
            accy[i][j] = (f32x4){0.f, 0.f, 0.f, 0.f};
    #pragma unroll
    for (int k0 = 0; k0 < 64; k0 += 32) {
        bf16x8 af[2], bfv[2];
        #pragma unroll
        for (int i = 0; i < 2; i++)
            af[i] = *(const bf16x8*)&sM[(wy * 32 + i * 16 + fr) * 72 + fk + k0];
        #pragma unroll
        for (int j = 0; j < 2; j++)
            bfv[j] = *(const bf16x8*)&sXT[(wx * 32 + j * 16 + fr) * 72 + fk + k0];
        #pragma unroll
        for (int i = 0; i < 2; i++)
            #pragma unroll
            for (int j = 0; j < 2; j++)
                accy[i][j] = __builtin_amdgcn_mfma_f32_16x16x32_bf16(
                    af[i], bfv[j], accy[i][j], 0, 0, 0);
    }
    #pragma unroll
    for (int k0 = 0; k0 < 128; k0 += 32) {
        bf16x8 af[2], bfv[2];
        #pragma unroll
        for (int i = 0; i < 2; i++)
            af[i] = *(const bf16x8*)&sC[(wy * 32 + i * 16 + fr) * 136 + fk + k0];
        #pragma unroll
        for (int j = 0; j < 2; j++)
            bfv[j] = *(const bf16x8*)&sH[(wx * 32 + j * 16 + fr) * 136 + fk + k0];
        #pragma unroll
        for (int i = 0; i < 2; i++)
            #pragma unroll
            for (int j = 0; j < 2; j++)
                accy[i][j] = __builtin_amdgcn_mfma_f32_16x16x32_bf16(
                    af[i], bfv[j], accy[i][j], 0, 0, 0);
    }

    #pragma unroll
    for (int i = 0; i < 2; i++) {
        #pragma unroll
        for (int j = 0; j < 2; j++) {
            #pragma unroll
            for (int r = 0; r < 4; r++) {
                const int l = wy * 32 + i * 16 + cr + r;
                const int p = wx * 32 + j * 16 + fr;
                const float x = bfu2f(sXT[p * 72 + l]);
                ybuf[(size_t)(tok0 + l) * DINNER + h * HEADDIM + p] =
                    __float2bfloat16(accy[i][j][r] + Dv * x);
            }
        }
    }
}

// ---- ynorm = rmsnorm(y * silu(z)) over 2048 dims -> bf16 (z f32, ld DINNER) ----
__global__ __launch_bounds__(256) void gated_rmsnorm_kernel(
    const bf16* __restrict__ y, const float* __restrict__ zf,
    const float* __restrict__ w, bf16* __restrict__ out)
{
    const int token = blockIdx.x, t = threadIdx.x;
    const bf16* yr = y + (size_t)token * DINNER;
    const float* zr = zf + (size_t)token * DINNER;
    float v[8]; float ss = 0.f;
    #pragma unroll
    for (int i = 0; i < 8; i++) {
        const int idx = t * 8 + i;
        const float zz = zr[idx];
        const float val = bf2f(yr[idx]) * (zz / (1.f + expf(-zz)));
        v[i] = val; ss += val * val;
    }
    ss = block_reduce_sum(ss);
    const float scale = rsqrtf(ss * (1.0f / DINNER) + 1e-6f);
    #pragma unroll
    for (int i = 0; i < 8; i++) {
        const int idx = t * 8 + i;
        out[(size_t)token * DINNER + idx] =
            __float2bfloat16(v[i] * scale * w[idx]);
    }
}

extern "C" void kernel_launch(void* const* d_in, const int* in_sizes, int n_in,
                              void* d_out, int out_size, void* d_ws, size_t ws_size,
                              hipStream_t stream) {
    const float* hidden     = (const float*)d_in[0];
    const float* norm_w     = (const float*)d_in[1];
    const float* in_proj_w  = (const float*)d_in[2];
    const float* conv_w     = (const float*)d_in[3];
    const float* conv_b     = (const float*)d_in[4];
    const float* dt_bias    = (const float*)d_in[5];
    const float* A_log      = (const float*)d_in[6];
    const float* Dh         = (const float*)d_in[7];
    const float* ssm_norm_w = (const float*)d_in[8];
    const float* out_proj_w = (const float*)d_in[9];
    const float* post_norm_w= (const float*)d_in[10];
    const float* gate_w     = (const float*)d_in[11];
    const float* up_w       = (const float*)d_in[12];
    const float* down_w     = (const float*)d_in[13];
    float* out = (float*)d_out;

    // ---- workspace layout (fl units) ----
    float* ws = (float*)d_ws;
    bf16*  h_norm = (bf16*)(ws);                 // [0, 1,048,576)
    float* zf     = ws + 1048576;                // f32 z 2048x2048 -> [.., 5,242,880)
    ushort_t* xbc = (ushort_t*)(ws + 5242880);   // bf16 2048x2304 -> [.., 7,602,176)
    float* dtraw  = ws + 7602176;                // f32 2048x32    -> [.., 7,667,712)
    ushort_t* cvb = (ushort_t*)(ws + 10027008);  // bf16 2048x2304
    float* dtb    = ws + 14745600;               // [14,745,600, 14,811,136)
    float* ccum   = ws + 14811136;               // 1024 fl
    ushort_t* Sbuf= (ushort_t*)(ws + 14812160);  // [14,812,160, 19,006,464) bf16
    float* xbuf   = ws + 19006464;               // [19,006,464, 21,103,616)
    bf16*  ybuf   = (bf16*)(ws + 21103616);      // [21,103,616, 22,152,192)
    bf16*  ynorm  = (bf16*)(ws + 22152192);      // [22,152,192, 23,200,768)
    // just-in-time bf16 weights in dead regions (zf/xbc dead after step 6):
    ushort_t* Wip = (ushort_t*)(ws + 10027008);  // cvb region, dead before conv
    ushort_t* Wop = (ushort_t*)(ws + 1048576);   // over zf (dead after step 6)
    ushort_t* Wgu = (ushort_t*)(ws + 2097152);   // interleaved gate/up
    ushort_t* Wdn = (ushort_t*)(ws + 4915200);   // over zf tail/xbc head (dead)
    bf16*  act    = (bf16*)(ws + 6324224);       // over xbc/dtraw (dead)
    bf16*  h2     = h_norm;                      // reuse

    // 0+1. fused: h = rmsnorm(hidden) -> bf16  AND  Wip = bf16(in_proj_w)
    prep_kernel<<<NTOK + 4384, 256, 0, stream>>>(hidden, norm_w, h_norm,
                                                 in_proj_w, Wip);
    // 2. zxbcdt = h @ Wip^T, split output: z f32 / xBC bf16 / dt_raw f32
    gemm_bf<3, 128, 128><<<dim3(35, 16), 256, 0, stream>>>(h_norm, (const bf16*)Wip,
        zf, dtraw, (bf16*)xbc, NTOK, DINPROJ, DMODEL);
    // 3+4. conv(k=4)+bias+silu (bf16 in, vectorized x4) fused with dt softplus
    conv_silu_dt_kernel<<<NCONVBLK + (NTOK * NHEADS) / 256, 256, 0, stream>>>(
        xbc, dtraw, conv_w, conv_b, dt_bias, cvb, dtb);
    // 5. chunked selective scan -> ybuf (bf16)
    chunk_state_kernel<<<1024, 256, 0, stream>>>(cvb, dtb, A_log, ccum, Sbuf);
    stitch_kernel<<<512, 256, 0, stream>>>(ccum, Sbuf);
    chunk_scan_mfma_kernel<<<1024, 256, 0, stream>>>(cvb, dtb, A_log, Dh, Sbuf, ybuf);
    // 6. ynorm = rmsnorm(y * silu(z), ssm_norm_w)  -> bf16 (last use of zf)
    gated_rmsnorm_kernel<<<NTOK, 256, 0, stream>>>(ybuf, zf, ssm_norm_w, ynorm);
    // 6b. convert out_proj/gate+up(interleaved)/down weights (fused)
    convert_weights_kernel<<<(NWOP + 3 * NWG) / 1024, 256, 0, stream>>>(
        out_proj_w, gate_w, up_w, down_w, Wop, Wgu, Wdn);
    // 7. x = hidden + ynorm @ Wop^T  (f32), 64x64 NKT=2 (K=2048) -> 512 blocks
    gemm_bf_s<2><<<dim3(16, 32), 256, 0, stream>>>(ynorm, (const bf16*)Wop, xbuf,
        hidden, NTOK, DMODEL, DINNER);
    // 8. h2 = rmsnorm(x, post_norm_w)  -> bf16
    rmsnorm1024_kernel<<<NTOK, 256, 0, stream>>>(xbuf, post_norm_w, h2);
    // 9+10. act = swiglu(h2 @ Wgu^T)  (fused epilogue, interleaved N=5504)
    gemm_bf<2, 128, 128><<<dim3(43, 16), 256, 0, stream>>>(h2, (const bf16*)Wgu,
        nullptr, nullptr, act, NTOK, 2 * INTER, DMODEL);
    // 11. out = x + act @ Wdn^T   (f32 to d_out), 64x64 NKT=1 (K=2752)
    gemm_bf_s<1><<<dim3(16, 32), 256, 0, stream>>>(act, (const bf16*)Wdn, out,
        xbuf, NTOK, DMODEL, INTER);
}

// Round 12
// 319.614 us; speedup vs baseline: 1.0474x; 1.0474x over previous
//
#include <hip/hip_runtime.h>
#include <hip/hip_bf16.h>

// ---- problem constants ----
#define SEQLEN   1024
#define NTOK     2048          // BATCH * SEQLEN
#define DMODEL   1024
#define DSTATE   128
#define DINNER   2048
#define NHEADS   32
#define HEADDIM  64
#define CONVDIM  2304          // DINNER + 2*DSTATE
#define DINPROJ  4384          // 2*DINNER + 2*DSTATE + NHEADS
#define INTER    2752
#define INTERP   2816          // INTER padded to 44*64 (zero tail) for NKT=2
#define Q        64            // scan chunk length
#define NCHUNK   16            // SEQLEN / Q

typedef __hip_bfloat16 bf16;
typedef unsigned short ushort_t;
typedef __attribute__((ext_vector_type(8))) short bf16x8;
typedef __attribute__((ext_vector_type(4))) float f32x4;
typedef __attribute__((ext_vector_type(4))) unsigned short u16x4;

__device__ __forceinline__ float bf2f(bf16 x) { return __bfloat162float(x); }
__device__ __forceinline__ float bfu2f(ushort_t u) {
    return __uint_as_float(((unsigned)u) << 16);
}
__device__ __forceinline__ ushort_t f2bfu(float x) {
    union { bf16 h; ushort_t u; } c; c.h = __float2bfloat16(x); return c.u;
}

__device__ __forceinline__ void glds16(const void* g, void* l) {
    __builtin_amdgcn_global_load_lds(
        (const __attribute__((address_space(1))) void*)g,
        (__attribute__((address_space(3))) void*)l, 16, 0, 0);
}

// counted-vmcnt pipeline fence (T3+T4) for the fat-tile GEMM.
template <int N>
__device__ __forceinline__ void pipe_fence() {
    if constexpr (N == 4)
        asm volatile("s_waitcnt vmcnt(4) lgkmcnt(0)" ::: "memory");
    else if constexpr (N == 2)
        asm volatile("s_waitcnt vmcnt(2) lgkmcnt(0)" ::: "memory");
    else
        asm volatile("s_waitcnt vmcnt(0) lgkmcnt(0)" ::: "memory");
    __builtin_amdgcn_s_barrier();
    __builtin_amdgcn_sched_barrier(0);
}

__device__ inline float block_reduce_sum(float v) {
    __shared__ float red[4];
    #pragma unroll
    for (int off = 32; off >= 1; off >>= 1) v += __shfl_down(v, off);
    int lane = threadIdx.x & 63, w = threadIdx.x >> 6;
    if (lane == 0) red[w] = v;
    __syncthreads();
    return red[0] + red[1] + red[2] + red[3];
}

// ---- fused: rmsnorm(hidden) -> h_norm  (blocks [0,2048))
//      + fp32->bf16 in_proj weight convert (blocks [2048, 2048+4384)) ----
__global__ __launch_bounds__(256) void prep_kernel(
    const float* __restrict__ hidden, const float* __restrict__ norm_w,
    bf16* __restrict__ h_norm,
    const float* __restrict__ wsrc, ushort_t* __restrict__ wdst)
{
    const int bid = blockIdx.x, t = threadIdx.x;
    if (bid < NTOK) {
        const int token = bid;
        float v[4]; float ss = 0.f;
        #pragma unroll
        for (int i = 0; i < 4; i++) {
            v[i] = hidden[(size_t)token * DMODEL + t * 4 + i];
            ss += v[i] * v[i];
        }
        ss = block_reduce_sum(ss);
        const float scale = rsqrtf(ss * (1.0f / DMODEL) + 1e-6f);
        #pragma unroll
        for (int i = 0; i < 4; i++)
            h_norm[(size_t)token * DMODEL + t * 4 + i] =
                __float2bfloat16(v[i] * scale * norm_w[t * 4 + i]);
    } else {
        const int i = ((bid - NTOK) * 256 + t) * 4;
        if (i < DINPROJ * DMODEL) {
            const f32x4 v = *(const f32x4*)(wsrc + i);
            u16x4 o;
            #pragma unroll
            for (int k = 0; k < 4; k++) o[k] = f2bfu(v[k]);
            *(u16x4*)(wdst + i) = o;
        }
    }
}

// ---- fused convert: out_proj / gate(even) / up(odd) / down (ld INTERP)
//      + zero-fill of Wdn and act K-pads (cols INTER..INTERP-1) ----
#define NWOP (DMODEL * DINNER)     // 2,097,152
#define NWG  (INTER * DMODEL)      // 2,818,048
#define WDN_PAD (DMODEL * 64)      // 65,536
#define ACT_PAD (NTOK * 64)        // 131,072
__global__ __launch_bounds__(256) void convert_weights_kernel(
    const float* __restrict__ wop, const float* __restrict__ wg,
    const float* __restrict__ wu, const float* __restrict__ wd,
    ushort_t* __restrict__ dWop, ushort_t* __restrict__ dWgu,
    ushort_t* __restrict__ dWdn, ushort_t* __restrict__ dAct)
{
    const int i4 = (blockIdx.x * 256 + threadIdx.x) * 4;
    const float* src;
    ushort_t* dst;
    if (i4 < NWOP) { src = wop + i4; dst = dWop + i4; }
    else if (i4 < NWOP + NWG) {
        const int e = i4 - NWOP, row = e >> 10, col = e & 1023;
        src = wg + e; dst = dWgu + ((size_t)(2 * row) << 10) + col;
    } else if (i4 < NWOP + 2 * NWG) {
        const int e = i4 - NWOP - NWG, row = e >> 10, col = e & 1023;
        src = wu + e; dst = dWgu + ((size_t)(2 * row + 1) << 10) + col;
    } else if (i4 < NWOP + 3 * NWG) {
        const int e = i4 - NWOP - 2 * NWG;
        const int row = e / INTER, col = e - row * INTER;
        src = wd + e; dst = dWdn + (size_t)row * INTERP + col;
    } else if (i4 < NWOP + 3 * NWG + WDN_PAD) {
        const int e = i4 - (NWOP + 3 * NWG);
        const int row = e >> 6;
        *(u16x4*)(dWdn + (size_t)row * INTERP + INTER + (e & 63)) =
            (u16x4){0, 0, 0, 0};
        return;
    } else if (i4 < NWOP + 3 * NWG + WDN_PAD + ACT_PAD) {
        const int e = i4 - (NWOP + 3 * NWG + WDN_PAD);
        const int row = e >> 6;
        *(u16x4*)(dAct + (size_t)row * INTERP + INTER + (e & 63)) =
            (u16x4){0, 0, 0, 0};
        return;
    } else return;
    const f32x4 v = *(const f32x4*)src;
    u16x4 o;
    #pragma unroll
    for (int k = 0; k < 4; k++) o[k] = f2bfu(v[k]);
    *(u16x4*)dst = o;
}

// ---- RMSNorm over 1024 dims (fp32 in, fp32 weights) -> bf16 out ----
__global__ __launch_bounds__(256) void rmsnorm1024_kernel(
    const float* __restrict__ x, const float* __restrict__ w, bf16* __restrict__ out)
{
    const int token = blockIdx.x, t = threadIdx.x;
    float v[4]; float ss = 0.f;
    #pragma unroll
    for (int i = 0; i < 4; i++) {
        v[i] = x[(size_t)token * DMODEL + t * 4 + i];
        ss += v[i] * v[i];
    }
    ss = block_reduce_sum(ss);
    const float scale = rsqrtf(ss * (1.0f / DMODEL) + 1e-6f);
    #pragma unroll
    for (int i = 0; i < 4; i++)
        out[(size_t)token * DMODEL + t * 4 + i] =
            __float2bfloat16(v[i] * scale * w[t * 4 + i]);
}

// ---- FAT GEMM: MT x NT, BK=32, 3-buffer 2-deep counted-vmcnt + setprio ----
// LDS [row][4 chunks of 8 ushorts]; stored chunk = src ^ ((row>>1)&3);
// read chunk = fq ^ ((fr>>1)&3) -> conflict-free (both-sides swizzle).
// EPI 2: swiglu -> out_bf (interleaved W, output ld INTERP)
// EPI 3: in_proj split output: z f32 / xBC bf16 / dt_raw f32
template <int EPI, int MT, int NT>
__global__ __launch_bounds__(256) void gemm_bf(
    const bf16* __restrict__ A, const bf16* __restrict__ W,
    float* __restrict__ Cf, float* __restrict__ aux_f,
    bf16* __restrict__ out_bf, int M, int N, int K)
{
    __shared__ ushort_t As[3][MT * 32];
    __shared__ ushort_t Bs[3][NT * 32];
    const int tid = threadIdx.x;
    const int w = tid >> 6, lane = tid & 63;
    constexpr int NLD = MT / 64 + NT / 64;   // glds instrs per wave per K-tile

    // XCD swizzle (bijective; m-major within each XCD chunk)
    const int gdx = gridDim.x, gdy = gridDim.y;
    const int nwg = gdx * gdy;
    const int orig = blockIdx.x + gdx * blockIdx.y;
    const int q8 = nwg >> 3, r8 = nwg & 7;
    const int xcd = orig & 7, lin = orig >> 3;
    const int wg = (xcd < r8 ? xcd * (q8 + 1) : r8 * (q8 + 1) + (xcd - r8) * q8) + lin;
    const int m0 = (wg % gdy) * MT;
    const int n0 = (wg / gdy) * NT;

    const int srow = tid >> 2;                               // 0..63
    const int scol = (((tid & 3) ^ ((srow >> 1) & 3)) * 8);  // swizzled src col
    const bf16* Agp[MT / 64];
    const bf16* Wgp[NT / 64];
    #pragma unroll
    for (int i = 0; i < MT / 64; i++)
        Agp[i] = A + (size_t)(m0 + i * 64 + srow) * K + scol;
    #pragma unroll
    for (int i = 0; i < NT / 64; i++) {
        const int nr = n0 + i * 64 + srow;
        Wgp[i] = W + (size_t)(nr < N ? nr : 0) * K + scol;
    }

    const int wy = w >> 1, wx = w & 1;
    const int fr = lane & 15;
    const int fq = lane >> 4;            // k-chunk (x8 ushorts) within K=32
    const int cxor = (fr >> 1) & 3;      // read-side swizzle (row-derived)
    constexpr int MI = MT / 32;
    constexpr int NJ = NT / 32;
    f32x4 acc[MI][NJ];
    #pragma unroll
    for (int i = 0; i < MI; i++)
        #pragma unroll
        for (int j = 0; j < NJ; j++)
            acc[i][j] = (f32x4){0.f, 0.f, 0.f, 0.f};

    const int nk = K >> 5;

    #define STAGE(buf, koff) do {                                         \
        ushort_t* sa_ = &As[buf][w * 512];                                \
        ushort_t* sb_ = &Bs[buf][w * 512];                                \
        _Pragma("unroll")                                                 \
        for (int i_ = 0; i_ < MT / 64; i_++)                              \
            glds16(Agp[i_] + (koff), sa_ + i_ * 2048);                    \
        _Pragma("unroll")                                                 \
        for (int i_ = 0; i_ < NT / 64; i_++)                              \
            glds16(Wgp[i_] + (koff), sb_ + i_ * 2048);                    \
    } while (0)

    STAGE(0, 0);
    STAGE(1, 32);
    pipe_fence<NLD>();

    int cur = 0, stg = 2;
    for (int kt = 0; kt < nk; ++kt) {
        const bool pf = (kt + 2 < nk);
        if (pf) STAGE(stg, (kt + 2) << 5);
        const ushort_t* ca = As[cur];
        const ushort_t* cb = Bs[cur];
        bf16x8 af[MI], bfv[NJ];
        #pragma unroll
        for (int i = 0; i < MI; i++) {
            const int r = wy * (MT / 2) + i * 16 + fr;
            af[i] = *(const bf16x8*)&ca[r * 32 + ((fq ^ cxor) * 8)];
        }
        #pragma unroll
        for (int j = 0; j < NJ; j++) {
            const int r = wx * (NT / 2) + j * 16 + fr;
            bfv[j] = *(const bf16x8*)&cb[r * 32 + ((fq ^ cxor) * 8)];
        }
        __builtin_amdgcn_s_setprio(1);   // T5: favor MFMA vs other blocks' staging
        #pragma unroll
        for (int i = 0; i < MI; i++)
            #pragma unroll
            for (int j = 0; j < NJ; j++)
                acc[i][j] = __builtin_amdgcn_mfma_f32_16x16x32_bf16(
                    af[i], bfv[j], acc[i][j], 0, 0, 0);
        __builtin_amdgcn_s_setprio(0);
        if (pf)               pipe_fence<NLD>();
        else if (kt + 1 < nk) pipe_fence<0>();
        cur = (cur == 2) ? 0 : cur + 1;
        stg = (stg == 2) ? 0 : stg + 1;
    }
    #undef STAGE

    // C/D layout: col = lane&15, row = (lane>>4)*4 + reg
    #pragma unroll
    for (int i = 0; i < MI; i++) {
        #pragma unroll
        for (int j = 0; j < NJ; j++) {
            const int mb = m0 + wy * (MT / 2) + i * 16 + (lane >> 4) * 4;
            const int nn = n0 + wx * (NT / 2) + j * 16 + (lane & 15);
            if (nn < N) {
                #pragma unroll
                for (int r = 0; r < 4; r++) {
                    if (EPI == 2) {
                        const float g = acc[i][j][r];
                        const float u = __shfl_xor(g, 1);
                        if (!(lane & 1)) {
                            const float a = (g / (1.f + expf(-g))) * u;
                            out_bf[(size_t)(mb + r) * INTERP + (nn >> 1)] =
                                __float2bfloat16(a);
                        }
                    } else {   // EPI == 3: split in_proj output
                        const float v = acc[i][j][r];
                        if (n0 < DINNER) {
                            Cf[(size_t)(mb + r) * DINNER + nn] = v;
                        } else if (n0 < DINNER + CONVDIM) {
                            out_bf[(size_t)(mb + r) * CONVDIM + (nn - DINNER)] =
                                __float2bfloat16(v);
                        } else {
                            aux_f[(size_t)(mb + r) * NHEADS +
                                  (nn - (DINNER + CONVDIM))] = v;
                        }
                    }
                }
            }
        }
    }
}

// ---- SMALL GEMM: 64x64 tile, NKT x 64 K-cols per barrier pair, 2-buf.
// NKT=2 for K%128==0 (16 MFMA/fence). Cf = acc + resid.
template <int NKT>
__global__ __launch_bounds__(256) void gemm_bf_s(
    const bf16* __restrict__ A, const bf16* __restrict__ W,
    float* __restrict__ Cf, const float* __restrict__ resid_f,
    int M, int N, int K)
{
    constexpr int MT = 64, NT = 64;
    __shared__ ushort_t As[2][MT * 64 * NKT];
    __shared__ ushort_t Bs[2][NT * 64 * NKT];
    const int tid = threadIdx.x;
    const int w = tid >> 6, lane = tid & 63;

    const int gdx = gridDim.x, gdy = gridDim.y;
    const int nwg = gdx * gdy;
    const int orig = blockIdx.x + gdx * blockIdx.y;
    const int q8 = nwg >> 3, r8 = nwg & 7;
    const int xcd = orig & 7, lin = orig >> 3;
    const int wg = (xcd < r8 ? xcd * (q8 + 1) : r8 * (q8 + 1) + (xcd - r8) * q8) + lin;
    const int m0 = (wg % gdy) * MT;
    const int n0 = (wg / gdy) * NT;

    const int srow = tid >> 3;                               // 0..31
    const int scol = (((tid & 7) ^ (srow & 7)) * 8);
    const bf16* Agp[2];
    const bf16* Wgp[2];
    #pragma unroll
    for (int i = 0; i < 2; i++)
        Agp[i] = A + (size_t)(m0 + i * 32 + srow) * K + scol;
    #pragma unroll
    for (int i = 0; i < 2; i++) {
        const int nr = n0 + i * 32 + srow;
        Wgp[i] = W + (size_t)(nr < N ? nr : 0) * K + scol;
    }

    const int wy = w >> 1, wx = w & 1;
    const int fr = lane & 15;
    const int fq = lane >> 4;
    f32x4 acc[2][2];
    #pragma unroll
    for (int i = 0; i < 2; i++)
        #pragma unroll
        for (int j = 0; j < 2; j++)
            acc[i][j] = (f32x4){0.f, 0.f, 0.f, 0.f};

    const int nk = K / (64 * NKT);

    #define STAGE_S(buf, koff) do {                                       \
        _Pragma("unroll")                                                 \
        for (int s_ = 0; s_ < NKT; s_++) {                                \
            _Pragma("unroll")                                             \
            for (int i_ = 0; i_ < 2; i_++) {                              \
                glds16(Agp[i_] + (koff) + s_ * 64,                        \
                       &As[buf][s_ * 4096 + i_ * 2048 + w * 512]);        \
                glds16(Wgp[i_] + (koff) + s_ * 64,                        \
                       &Bs[buf][s_ * 4096 + i_ * 2048 + w * 512]);        \
            }                                                             \
        }                                                                 \
    } while (0)

    STAGE_S(0, 0);
    __syncthreads();

    for (int kt = 0; kt < nk; ++kt) {
        const int cur = kt & 1;
        if (kt + 1 < nk) STAGE_S(cur ^ 1, (kt + 1) * (64 * NKT));
        const ushort_t* ca = As[cur];
        const ushort_t* cb = Bs[cur];
        #pragma unroll
        for (int s = 0; s < NKT; s++) {
            #pragma unroll
            for (int ks = 0; ks < 2; ks++) {
                bf16x8 af[2], bfv[2];
                #pragma unroll
                for (int i = 0; i < 2; i++) {
                    const int r = wy * 32 + i * 16 + fr;
                    const int g = ks * 4 + fq;
                    af[i] = *(const bf16x8*)&ca[s * 4096 + r * 64 + ((g ^ (r & 7)) * 8)];
                }
                #pragma unroll
                for (int j = 0; j < 2; j++) {
                    const int r = wx * 32 + j * 16 + fr;
                    const int g = ks * 4 + fq;
                    bfv[j] = *(const bf16x8*)&cb[s * 4096 + r * 64 + ((g ^ (r & 7)) * 8)];
                }
                #pragma unroll
                for (int i = 0; i < 2; i++)
                    #pragma unroll
                    for (int j = 0; j < 2; j++)
                        acc[i][j] = __builtin_amdgcn_mfma_f32_16x16x32_bf16(
                            af[i], bfv[j], acc[i][j], 0, 0, 0);
            }
        }
        __syncthreads();
    }
    #undef STAGE_S

    #pragma unroll
    for (int i = 0; i < 2; i++) {
        #pragma unroll
        for (int j = 0; j < 2; j++) {
            const int mb = m0 + wy * 32 + i * 16 + (lane >> 4) * 4;
            const int nn = n0 + wx * 32 + j * 16 + (lane & 15);
            if (nn < N) {
                #pragma unroll
                for (int r = 0; r < 4; r++) {
                    const size_t idx = (size_t)(mb + r) * N + nn;
                    Cf[idx] = acc[i][j][r] + resid_f[idx];
                }
            }
        }
    }
}

// ---- fused: depthwise causal conv (k=4)+bias+silu (4 ch/thread, bf16 in)
//      + dt = softplus(dt_raw + dt_bias) in trailing blocks (f32 dense in) ----
#define NCONVBLK ((NTOK * CONVDIM / 4) / 256)    // 4608
__global__ __launch_bounds__(256) void conv_silu_dt_kernel(
    const ushort_t* __restrict__ xbc, const float* __restrict__ dtraw,
    const float* __restrict__ cw, const float* __restrict__ cb,
    const float* __restrict__ dtbias,
    ushort_t* __restrict__ out, float* __restrict__ dtb_out)
{
    const int bid = blockIdx.x;
    if (bid < NCONVBLK) {
        const int i = bid * 256 + threadIdx.x;       // 0 .. NTOK*CONVDIM/4
        const int cg = i % (CONVDIM / 4);
        const int token = i / (CONVDIM / 4);
        const int c0 = cg * 4;
        const int l = token & (SEQLEN - 1);
        float a[4];
        #pragma unroll
        for (int j = 0; j < 4; j++) a[j] = cb[c0 + j];
        f32x4 cwv[4];
        #pragma unroll
        for (int j = 0; j < 4; j++) cwv[j] = *(const f32x4*)(cw + (c0 + j) * 4);
        #pragma unroll
        for (int k = 0; k < 4; k++) {
            const int ls = l - 3 + k;
            if (ls >= 0) {
                const u16x4 v = *(const u16x4*)(
                    xbc + (size_t)(token - 3 + k) * CONVDIM + c0);
                #pragma unroll
                for (int j = 0; j < 4; j++) a[j] += bfu2f(v[j]) * cwv[j][k];
            }
        }
        u16x4 o;
        #pragma unroll
        for (int j = 0; j < 4; j++)
            o[j] = f2bfu(a[j] / (1.f + expf(-a[j])));
        *(u16x4*)(out + (size_t)token * CONVDIM + c0) = o;
    } else {
        const int idx = (bid - NCONVBLK) * 256 + threadIdx.x;   // NTOK*NHEADS
        const int h = idx & (NHEADS - 1);
        const float v = dtraw[idx] + dtbias[h];
        dtb_out[idx] = (v > 20.f) ? v : log1pf(expf(v));
    }
}

// ================= chunked scan =================
// Phase A (MFMA): S[p,n] = sum_l (w_l x[l,p]) B[l,n],  w_l = exp(cumQ-cum_l)*dt_l
__global__ __launch_bounds__(256) void chunk_state_kernel(
    const ushort_t* __restrict__ cvb, const float* __restrict__ dtb,
    const float* __restrict__ A_log, float* __restrict__ ccum,
    ushort_t* __restrict__ Sbuf)
{
    const int bx = blockIdx.x;
    const int bh = bx >> 4, c = bx & 15;
    const int b = bh >> 5, h = bh & 31;
    const int t = threadIdx.x;
    const int w = t >> 6, lane = t & 63;
    const int wy = w >> 1, wx = w & 1;
    const int fr = lane & 15, fk = (lane >> 4) * 8, cr = (lane >> 4) * 4;
    const int tok0 = b * SEQLEN + c * Q;
    const float A = -expf(A_log[h]);

    __shared__ ushort_t sXT[64 * 88];    // [p][l], weighted
    __shared__ ushort_t sBT[128 * 88];   // [n][l]
    __shared__ float sW[64];

    if (t < 64) {
        const float d = dtb[(size_t)(tok0 + t) * NHEADS + h];
        float s = d;
        #pragma unroll
        for (int off = 1; off < 64; off <<= 1) {
            const float up = __shfl_up(s, off);
            if (t >= off) s += up;
        }
        const float total = __shfl(s, 63);
        sW[t] = expf(A * (total - s)) * d;     // arg <= 0
        if (t == 63) ccum[bh * NCHUNK + c] = A * total;
    }
    __syncthreads();

    for (int i = t; i < 64 * 64; i += 256) {
        const int l = i >> 6, p = i & 63;
        const float v = bfu2f(cvb[(size_t)(tok0 + l) * CONVDIM + h * HEADDIM + p]);
        sXT[p * 88 + l] = f2bfu(sW[l] * v);
    }
    for (int i = t; i < 128 * 64; i += 256) {
        const int l = i >> 7, n = i & 127;
        sBT[n * 88 + l] = cvb[(size_t)(tok0 + l) * CONVDIM + DINNER + n];
    }
    __syncthreads();

    f32x4 acc[2][4];
    #pragma unroll
    for (int i = 0; i < 2; i++)
        #pragma unroll
        for (int j = 0; j < 4; j++)
            acc[i][j] = (f32x4){0.f, 0.f, 0.f, 0.f};
    #pragma unroll
    for (int k0 = 0; k0 < 64; k0 += 32) {
        bf16x8 af[2], bfv[4];
        #pragma unroll
        for (int i = 0; i < 2; i++)
            af[i] = *(const bf16x8*)&sXT[(wy * 32 + i * 16 + fr) * 88 + fk + k0];
        #pragma unroll
        for (int j = 0; j < 4; j++)
            bfv[j] = *(const bf16x8*)&sBT[(wx * 64 + j * 16 + fr) * 88 + fk + k0];
        #pragma unroll
        for (int i = 0; i < 2; i++)
            #pragma unroll
            for (int j = 0; j < 4; j++)
                acc[i][j] = __builtin_amdgcn_mfma_f32_16x16x32_bf16(
                    af[i], bfv[j], acc[i][j], 0, 0, 0);
    }
    const size_t slot = (size_t)(bh * NCHUNK + c) * 64 * 128;
    #pragma unroll
    for (int i = 0; i < 2; i++) {
        #pragma unroll
        for (int j = 0; j < 4; j++) {
            #pragma unroll
            for (int r = 0; r < 4; r++) {
                const int pr = wy * 32 + i * 16 + cr + r;
                const int nn = wx * 64 + j * 16 + fr;
                Sbuf[slot + pr * 128 + nn] = f2bfu(acc[i][j][r]);
            }
        }
    }
}

// Phase B: sequential stitch; writes incoming H_c into slot c.
// 4-way split; P factors precomputed; chunk c+1's load issued BEFORE
// chunk c's store (one iteration of latency slack).
__global__ __launch_bounds__(256) void stitch_kernel(
    const float* __restrict__ ccum, ushort_t* __restrict__ Sbuf)
{
    const int bh = blockIdx.x >> 2, ng = blockIdx.x & 3;
    const int t = threadIdx.x, p = t >> 2, q = t & 3;
    float P[NCHUNK];
    #pragma unroll
    for (int c = 0; c < NCHUNK; c++) P[c] = expf(ccum[bh * NCHUNK + c]);
    float H[8];
    #pragma unroll
    for (int j = 0; j < 8; j++) H[j] = 0.f;

    const size_t off0 = (size_t)p * 128 + ng * 32 + q * 4;
    #define SLOT(c) (((size_t)(bh * NCHUNK + (c)) * 64) * 128 + off0)
    u16x4 nv0 = *(const u16x4*)&Sbuf[SLOT(0)];
    u16x4 nv1 = *(const u16x4*)&Sbuf[SLOT(0) + 16];
    for (int c = 0; c < NCHUNK; c++) {
        const u16x4 sv0 = nv0, sv1 = nv1;
        if (c + 1 < NCHUNK) {
            nv0 = *(const u16x4*)&Sbuf[SLOT(c + 1)];
            nv1 = *(const u16x4*)&Sbuf[SLOT(c + 1) + 16];
        }
        u16x4 hv0, hv1;
        #pragma unroll
        for (int k = 0; k < 4; k++) { hv0[k] = f2bfu(H[k]); hv1[k] = f2bfu(H[4 + k]); }
        *(u16x4*)&Sbuf[SLOT(c)] = hv0;
        *(u16x4*)&Sbuf[SLOT(c) + 16] = hv1;
        #pragma unroll
        for (int k = 0; k < 4; k++) {
            H[k]     = P[c] * H[k]     + bfu2f(sv0[k]);
            H[4 + k] = P[c] * H[4 + k] + bfu2f(sv1[k]);
        }
    }
    #undef SLOT
}

// Phase C (MFMA): Y = mask(C@B^T)@X + (exp(cum)*C)@H^T + D*X
__global__ __launch_bounds__(256) void chunk_scan_mfma_kernel(
    const ushort_t* __restrict__ cvb, const float* __restrict__ dtb,
    const float* __restrict__ A_log, const float* __restrict__ Dh,
    const ushort_t* __restrict__ Sbuf, bf16* __restrict__ ybuf)
{
    const int bx = blockIdx.x;
    const int bh = bx >> 4, c = bx & 15;
    const int b = bh >> 5, h = bh & 31;
    const int t = threadIdx.x;
    const int w = t >> 6, lane = t & 63;
    const int wy = w >> 1, wx = w & 1;
    const int fr = lane & 15;
    const int fk = (lane >> 4) * 8;
    const int cr = (lane >> 4) * 4;
    const int tok0 = b * SEQLEN + c * Q;
    const float A = -expf(A_log[h]);
    const float Dv = Dh[h];

    __shared__ ushort_t sB[64 * 136];
    __shared__ ushort_t sC[64 * 136];
    __shared__ ushort_t sH[64 * 136];
    __shared__ ushort_t sXT[64 * 72];
    __shared__ ushort_t sM[64 * 72];
    __shared__ float    sCum[64];
    __shared__ float    sDtv[64];

    for (int i = t; i < 64 * 32; i += 256) {
        const int row = i >> 5, col = (i & 31) * 4;
        const size_t base = (size_t)(tok0 + row) * CONVDIM;
        *(u16x4*)&sB[row * 136 + col] = *(const u16x4*)&cvb[base + DINNER + col];
        *(u16x4*)&sC[row * 136 + col] = *(const u16x4*)&cvb[base + DINNER + DSTATE + col];
    }
    for (int i = t; i < 64 * 32; i += 256) {
        const int p = i >> 5, l0 = (i & 31) * 2;
        const ushort_t x0 = cvb[(size_t)(tok0 + l0)     * CONVDIM + h * HEADDIM + p];
        const ushort_t x1 = cvb[(size_t)(tok0 + l0 + 1) * CONVDIM + h * HEADDIM + p];
        *(unsigned*)&sXT[p * 72 + l0] = ((unsigned)x1 << 16) | x0;
    }
    {
        const size_t slot = (size_t)(bh * NCHUNK + c) * 64 * 128;
        for (int i = t * 4; i < 64 * 128; i += 1024) {
            const int row = i >> 7, col = i & 127;
            *(u16x4*)&sH[row * 136 + col] = *(const u16x4*)&Sbuf[slot + row * 128 + col];
        }
    }
    if (t < 64) {
        const float d = dtb[(size_t)(tok0 + t) * NHEADS + h];
        float s = d;
        #pragma unroll
        for (int off = 1; off < 64; off <<= 1) {
            const float up = __shfl_up(s, off);
            if (t >= off) s += up;
        }
        sCum[t] = A * s;
        sDtv[t] = d;
    }
    __syncthreads();

    // GEMM1: G = C @ B^T
    f32x4 accg[2][2];
    #pragma unroll
    for (int i = 0; i < 2; i++)
        #pragma unroll
        for (int j = 0; j < 2; j++)
            accg[i][j] = (f32x4){0.f, 0.f, 0.f, 0.f};
    #pragma unroll
    for (int k0 = 0; k0 < 128; k0 += 32) {
        bf16x8 af[2], bfv[2];
        #pragma unroll
        for (int i = 0; i < 2; i++)
            af[i] = *(const bf16x8*)&sC[(wy * 32 + i * 16 + fr) * 136 + fk + k0];
        #pragma unroll
        for (int j = 0; j < 2; j++)
            bfv[j] = *(const bf16x8*)&sB[(wx * 32 + j * 16 + fr) * 136 + fk + k0];
        #pragma unroll
        for (int i = 0; i < 2; i++)
            #pragma unroll
            for (int j = 0; j < 2; j++)
                accg[i][j] = __builtin_amdgcn_mfma_f32_16x16x32_bf16(
                    af[i], bfv[j], accg[i][j], 0, 0, 0);
    }
    __syncthreads();

    #pragma unroll
    for (int i = 0; i < 2; i++) {
        #pragma unroll
        for (int j = 0; j < 2; j++) {
            #pragma unroll
            for (int r = 0; r < 4; r++) {
                const int l  = wy * 32 + i * 16 + cr + r;
                const int jc = wx * 32 + j * 16 + fr;
                const float v = (jc <= l)
                    ? accg[i][j][r] * expf(sCum[l] - sCum[jc]) * sDtv[jc] : 0.f;
                sM[l * 72 + jc] = f2bfu(v);
            }
        }
    }
    for (int i = t; i < 64 * 32; i += 256) {
        const int row = i >> 5, col = (i & 31) * 4;
        const float sc = expf(sCum[row]);
        u16x4 v = *(const u16x4*)&sC[row * 136 + col];
        #pragma unroll
        for (int k = 0; k < 4; k++) v[k] = f2bfu(bfu2f(v[k]) * sc);
        *(u16x4*)&sC[row * 136 + col] = v;
    }
    __syncthreads();

    // GEMM2: Y = M @ X + (scaled C) @ H^T
    f32x4 accy[2][2];
    #pragma unroll
    for (int i = 0; i < 2; i++)
        #pragma unroll
        for (int j = 0; j < 2; j++)
            accy[i][j] = (f32x4){0.f, 0.f, 0.f, 0.f};
    #pragma unroll
    for (int k0 = 0; k0 < 64; k0 += 32) {
        bf16x8 af[2], bfv[2];
        #pragma unroll
        for (int i = 0; i < 2; i++)
            af[i] = *(const bf16x8*)&sM[(wy * 32 + i * 16 + fr) * 72 + fk + k0];
        #pragma unroll
        for (int j = 0; j < 2; j++)
            bfv[j] = *(const bf16x8*)&sXT[(wx * 32 + j * 16 + fr) * 72 + fk + k0];
        #pragma unroll
        for (int i = 0; i < 2; i++)
            #pragma unroll
            for (int j = 0; j < 2; j++)
                accy[i][j] = __builtin_amdgcn_mfma_f32_16x16x32_bf16(
                    af[i], bfv[j], accy[i][j], 0, 0, 0);
    }
    #pragma unroll
    for (int k0 = 0; k0 < 128; k0 += 32) {
        bf16x8 af[2], bfv[2];
        #pragma unroll
        for (int i = 0; i < 2; i++)
            af[i] = *(const bf16x8*)&sC[(wy * 32 + i * 16 + fr) * 136 + fk + k0];
        #pragma unroll
        for (int j = 0; j < 2; j++)
            bfv[j] = *(const bf16x8*)&sH[(wx * 32 + j * 16 + fr) * 136 + fk + k0];
        #pragma unroll
        for (int i = 0; i < 2; i++)
            #pragma unroll
            for (int j = 0; j < 2; j++)
                accy[i][j] = __builtin_amdgcn_mfma_f32_16x16x32_bf16(
                    af[i], bfv[j], accy[i][j], 0, 0, 0);
    }

    #pragma unroll
    for (int i = 0; i < 2; i++) {
        #pragma unroll
        for (int j = 0; j < 2; j++) {
            #pragma unroll
            for (int r = 0; r < 4; r++) {
                const int l = wy * 32 + i * 16 + cr + r;
                const int p = wx * 32 + j * 16 + fr;
                const float x = bfu2f(sXT[p * 72 + l]);
                ybuf[(size_t)(tok0 + l) * DINNER + h * HEADDIM + p] =
                    __float2bfloat16(accy[i][j][r] + Dv * x);
            }
        }
    }
}

// ---- ynorm = rmsnorm(y * silu(z)) over 2048 dims -> bf16 (z f32, ld DINNER) ----
__global__ __launch_bounds__(256) void gated_rmsnorm_kernel(
    const bf16* __restrict__ y, const float* __restrict__ zf,
    const float* __restrict__ w, bf16* __restrict__ out)
{
    const int token = blockIdx.x, t = threadIdx.x;
    const bf16* yr = y + (size_t)token * DINNER;
    const float* zr = zf + (size_t)token * DINNER;
    float v[8]; float ss = 0.f;
    #pragma unroll
    for (int i = 0; i < 8; i++) {
        const int idx = t * 8 + i;
        const float zz = zr[idx];
        const float val = bf2f(yr[idx]) * (zz / (1.f + expf(-zz)));
        v[i] = val; ss += val * val;
    }
    ss = block_reduce_sum(ss);
    const float scale = rsqrtf(ss * (1.0f / DINNER) + 1e-6f);
    #pragma unroll
    for (int i = 0; i < 8; i++) {
        const int idx = t * 8 + i;
        out[(size_t)token * DINNER + idx] =
            __float2bfloat16(v[i] * scale * w[idx]);
    }
}

extern "C" void kernel_launch(void* const* d_in, const int* in_sizes, int n_in,
                              void* d_out, int out_size, void* d_ws, size_t ws_size,
                              hipStream_t stream) {
    const float* hidden     = (const float*)d_in[0];
    const float* norm_w     = (const float*)d_in[1];
    const float* in_proj_w  = (const float*)d_in[2];
    const float* conv_w     = (const float*)d_in[3];
    const float* conv_b     = (const float*)d_in[4];
    const float* dt_bias    = (const float*)d_in[5];
    const float* A_log      = (const float*)d_in[6];
    const float* Dh         = (const float*)d_in[7];
    const float* ssm_norm_w = (const float*)d_in[8];
    const float* out_proj_w = (const float*)d_in[9];
    const float* post_norm_w= (const float*)d_in[10];
    const float* gate_w     = (const float*)d_in[11];
    const float* up_w       = (const float*)d_in[12];
    const float* down_w     = (const float*)d_in[13];
    float* out = (float*)d_out;

    // ---- workspace layout (fl units) ----
    float* ws = (float*)d_ws;
    bf16*  h_norm = (bf16*)(ws);                 // [0, 1,048,576)
    float* zf     = ws + 1048576;                // f32 z 2048x2048 -> [.., 5,242,880)
    ushort_t* xbc = (ushort_t*)(ws + 5242880);   // bf16 2048x2304 -> [.., 7,602,176)
    float* dtraw  = ws + 7602176;                // f32 2048x32    -> [.., 7,667,712)
    ushort_t* cvb = (ushort_t*)(ws + 10027008);  // bf16 2048x2304
    float* dtb    = ws + 14745600;               // [14,745,600, 14,811,136)
    float* ccum   = ws + 14811136;               // 1024 fl
    ushort_t* Sbuf= (ushort_t*)(ws + 14812160);  // [14,812,160, 19,006,464) bf16
    float* xbuf   = ws + 19006464;               // [19,006,464, 21,103,616)
    bf16*  ybuf   = (bf16*)(ws + 21103616);      // [21,103,616, 22,152,192)
    bf16*  ynorm  = (bf16*)(ws + 22152192);      // [22,152,192, 23,200,768)
    // just-in-time bf16 weights in dead regions (zf/xbc dead after step 6):
    ushort_t* Wip = (ushort_t*)(ws + 10027008);  // cvb region, dead before conv
    ushort_t* Wop = (ushort_t*)(ws + 1048576);   // over zf (dead after step 6)
    ushort_t* Wgu = (ushort_t*)(ws + 2097152);   // interleaved gate/up
    ushort_t* Wdn = (ushort_t*)(ws + 4915200);   // 1024x2816 -> [.., 6,356,992)
    bf16*  act    = (bf16*)(ws + 6356992);       // 2048x2816 -> [.., 9,240,576)
    bf16*  h2     = h_norm;                      // reuse

    // 0+1. fused: h = rmsnorm(hidden) -> bf16  AND  Wip = bf16(in_proj_w)
    prep_kernel<<<NTOK + 4384, 256, 0, stream>>>(hidden, norm_w, h_norm,
                                                 in_proj_w, Wip);
    // 2. zxbcdt = h @ Wip^T, split output: z f32 / xBC bf16 / dt_raw f32
    gemm_bf<3, 128, 128><<<dim3(35, 16), 256, 0, stream>>>(h_norm, (const bf16*)Wip,
        zf, dtraw, (bf16*)xbc, NTOK, DINPROJ, DMODEL);
    // 3+4. conv(k=4)+bias+silu (bf16 in, vectorized x4) fused with dt softplus
    conv_silu_dt_kernel<<<NCONVBLK + (NTOK * NHEADS) / 256, 256, 0, stream>>>(
        xbc, dtraw, conv_w, conv_b, dt_bias, cvb, dtb);
    // 5. chunked selective scan -> ybuf (bf16)
    chunk_state_kernel<<<1024, 256, 0, stream>>>(cvb, dtb, A_log, ccum, Sbuf);
    stitch_kernel<<<256, 256, 0, stream>>>(ccum, Sbuf);
    chunk_scan_mfma_kernel<<<1024, 256, 0, stream>>>(cvb, dtb, A_log, Dh, Sbuf, ybuf);
    // 6. ynorm = rmsnorm(y * silu(z), ssm_norm_w)  -> bf16 (last use of zf)
    gated_rmsnorm_kernel<<<NTOK, 256, 0, stream>>>(ybuf, zf, ssm_norm_w, ynorm);
    // 6b. convert out_proj/gate+up(interleaved)/down(ld 2816) + zero K-pads
    convert_weights_kernel<<<(NWOP + 3 * NWG + WDN_PAD + ACT_PAD) / 1024, 256, 0,
        stream>>>(out_proj_w, gate_w, up_w, down_w, Wop, Wgu, Wdn, (ushort_t*)act);
    // 7. x = hidden + ynorm @ Wop^T  (f32), 64x64 NKT=2 (K=2048) -> 512 blocks
    gemm_bf_s<2><<<dim3(16, 32), 256, 0, stream>>>(ynorm, (const bf16*)Wop, xbuf,
        hidden, NTOK, DMODEL, DINNER);
    // 8. h2 = rmsnorm(x, post_norm_w)  -> bf16
    rmsnorm1024_kernel<<<NTOK, 256, 0, stream>>>(xbuf, post_norm_w, h2);
    // 9+10. act = swiglu(h2 @ Wgu^T)  (fused epilogue, act ld = 2816)
    gemm_bf<2, 128, 128><<<dim3(43, 16), 256, 0, stream>>>(h2, (const bf16*)Wgu,
        nullptr, nullptr, act, NTOK, 2 * INTER, DMODEL);
    // 11. out = x + act @ Wdn^T  (f32 to d_out), 64x64 NKT=2 (K=2816, zero pad)
    gemm_bf_s<2><<<dim3(16, 32), 256, 0, stream>>>(act, (const bf16*)Wdn, out,
        xbuf, NTOK, DMODEL, INTERP);
}

// Round 14
// 313.661 us; speedup vs baseline: 1.0672x; 1.0190x over previous
//
#include <hip/hip_runtime.h>
#include <hip/hip_bf16.h>

// ---- problem constants ----
#define SEQLEN   1024
#define NTOK     2048          // BATCH * SEQLEN
#define DMODEL   1024
#define DSTATE   128
#define DINNER   2048
#define NHEADS   32
#define HEADDIM  64
#define CONVDIM  2304          // DINNER + 2*DSTATE
#define DINPROJ  4384          // 2*DINNER + 2*DSTATE + NHEADS
#define INTER    2752
#define INTERP   2816          // INTER padded to 44*64 (zero tail) for NKT=2
#define Q        64            // scan chunk length
#define NCHUNK   16            // SEQLEN / Q

typedef __hip_bfloat16 bf16;
typedef unsigned short ushort_t;
typedef __attribute__((ext_vector_type(8))) short bf16x8;
typedef __attribute__((ext_vector_type(4))) float f32x4;
typedef __attribute__((ext_vector_type(4))) unsigned short u16x4;

__device__ __forceinline__ float bf2f(bf16 x) { return __bfloat162float(x); }
__device__ __forceinline__ float bfu2f(ushort_t u) {
    return __uint_as_float(((unsigned)u) << 16);
}
__device__ __forceinline__ ushort_t f2bfu(float x) {
    union { bf16 h; ushort_t u; } c; c.h = __float2bfloat16(x); return c.u;
}

__device__ __forceinline__ void glds16(const void* g, void* l) {
    __builtin_amdgcn_global_load_lds(
        (const __attribute__((address_space(1))) void*)g,
        (__attribute__((address_space(3))) void*)l, 16, 0, 0);
}

// counted-vmcnt pipeline fence (T3+T4) for the fat-tile GEMM.
template <int N>
__device__ __forceinline__ void pipe_fence() {
    if constexpr (N == 4)
        asm volatile("s_waitcnt vmcnt(4) lgkmcnt(0)" ::: "memory");
    else if constexpr (N == 2)
        asm volatile("s_waitcnt vmcnt(2) lgkmcnt(0)" ::: "memory");
    else
        asm volatile("s_waitcnt vmcnt(0) lgkmcnt(0)" ::: "memory");
    __builtin_amdgcn_s_barrier();
    __builtin_amdgcn_sched_barrier(0);
}

__device__ inline float block_reduce_sum(float v) {
    __shared__ float red[4];
    #pragma unroll
    for (int off = 32; off >= 1; off >>= 1) v += __shfl_down(v, off);
    int lane = threadIdx.x & 63, w = threadIdx.x >> 6;
    if (lane == 0) red[w] = v;
    __syncthreads();
    return red[0] + red[1] + red[2] + red[3];
}

// ---- fused: rmsnorm(hidden) -> h_norm  (blocks [0,2048))
//      + fp32->bf16 in_proj weight convert (blocks [2048, 2048+4384)) ----
__global__ __launch_bounds__(256) void prep_kernel(
    const float* __restrict__ hidden, const float* __restrict__ norm_w,
    bf16* __restrict__ h_norm,
    const float* __restrict__ wsrc, ushort_t* __restrict__ wdst)
{
    const int bid = blockIdx.x, t = threadIdx.x;
    if (bid < NTOK) {
        const int token = bid;
        float v[4]; float ss = 0.f;
        #pragma unroll
        for (int i = 0; i < 4; i++) {
            v[i] = hidden[(size_t)token * DMODEL + t * 4 + i];
            ss += v[i] * v[i];
        }
        ss = block_reduce_sum(ss);
        const float scale = rsqrtf(ss * (1.0f / DMODEL) + 1e-6f);
        #pragma unroll
        for (int i = 0; i < 4; i++)
            h_norm[(size_t)token * DMODEL + t * 4 + i] =
                __float2bfloat16(v[i] * scale * norm_w[t * 4 + i]);
    } else {
        const int i = ((bid - NTOK) * 256 + t) * 4;
        if (i < DINPROJ * DMODEL) {
            const f32x4 v = *(const f32x4*)(wsrc + i);
            u16x4 o;
            #pragma unroll
            for (int k = 0; k < 4; k++) o[k] = f2bfu(v[k]);
            *(u16x4*)(wdst + i) = o;
        }
    }
}

// ---- fused convert: out_proj / gate(even) / up(odd) / down (ld INTERP)
//      + zero-fill of Wdn and act K-pads (cols INTER..INTERP-1) ----
#define NWOP (DMODEL * DINNER)     // 2,097,152
#define NWG  (INTER * DMODEL)      // 2,818,048
#define WDN_PAD (DMODEL * 64)      // 65,536
#define ACT_PAD (NTOK * 64)        // 131,072
__global__ __launch_bounds__(256) void convert_weights_kernel(
    const float* __restrict__ wop, const float* __restrict__ wg,
    const float* __restrict__ wu, const float* __restrict__ wd,
    ushort_t* __restrict__ dWop, ushort_t* __restrict__ dWgu,
    ushort_t* __restrict__ dWdn, ushort_t* __restrict__ dAct)
{
    const int i4 = (blockIdx.x * 256 + threadIdx.x) * 4;
    const float* src;
    ushort_t* dst;
    if (i4 < NWOP) { src = wop + i4; dst = dWop + i4; }
    else if (i4 < NWOP + NWG) {
        const int e = i4 - NWOP, row = e >> 10, col = e & 1023;
        src = wg + e; dst = dWgu + ((size_t)(2 * row) << 10) + col;
    } else if (i4 < NWOP + 2 * NWG) {
        const int e = i4 - NWOP - NWG, row = e >> 10, col = e & 1023;
        src = wu + e; dst = dWgu + ((size_t)(2 * row + 1) << 10) + col;
    } else if (i4 < NWOP + 3 * NWG) {
        const int e = i4 - NWOP - 2 * NWG;
        const int row = e / INTER, col = e - row * INTER;
        src = wd + e; dst = dWdn + (size_t)row * INTERP + col;
    } else if (i4 < NWOP + 3 * NWG + WDN_PAD) {
        const int e = i4 - (NWOP + 3 * NWG);
        const int row = e >> 6;
        *(u16x4*)(dWdn + (size_t)row * INTERP + INTER + (e & 63)) =
            (u16x4){0, 0, 0, 0};
        return;
    } else if (i4 < NWOP + 3 * NWG + WDN_PAD + ACT_PAD) {
        const int e = i4 - (NWOP + 3 * NWG + WDN_PAD);
        const int row = e >> 6;
        *(u16x4*)(dAct + (size_t)row * INTERP + INTER + (e & 63)) =
            (u16x4){0, 0, 0, 0};
        return;
    } else return;
    const f32x4 v = *(const f32x4*)src;
    u16x4 o;
    #pragma unroll
    for (int k = 0; k < 4; k++) o[k] = f2bfu(v[k]);
    *(u16x4*)dst = o;
}

// ---- RMSNorm over 1024 dims (fp32 in, fp32 weights) -> bf16 out ----
__global__ __launch_bounds__(256) void rmsnorm1024_kernel(
    const float* __restrict__ x, const float* __restrict__ w, bf16* __restrict__ out)
{
    const int token = blockIdx.x, t = threadIdx.x;
    float v[4]; float ss = 0.f;
    #pragma unroll
    for (int i = 0; i < 4; i++) {
        v[i] = x[(size_t)token * DMODEL + t * 4 + i];
        ss += v[i] * v[i];
    }
    ss = block_reduce_sum(ss);
    const float scale = rsqrtf(ss * (1.0f / DMODEL) + 1e-6f);
    #pragma unroll
    for (int i = 0; i < 4; i++)
        out[(size_t)token * DMODEL + t * 4 + i] =
            __float2bfloat16(v[i] * scale * w[t * 4 + i]);
}

// ---- FAT GEMM: MT x NT, BK=32, 3-buffer 2-deep counted-vmcnt + setprio ----
// LDS [row][4 chunks of 8 ushorts]; stored chunk = src ^ ((row>>1)&3);
// read chunk = fq ^ ((fr>>1)&3) -> conflict-free (both-sides swizzle).
// EPI 2: swiglu -> out_bf (interleaved W, output ld INTERP)
// EPI 3: in_proj split output: z f32 / xBC bf16 / dt_raw f32
template <int EPI, int MT, int NT>
__global__ __launch_bounds__(256) void gemm_bf(
    const bf16* __restrict__ A, const bf16* __restrict__ W,
    float* __restrict__ Cf, float* __restrict__ aux_f,
    bf16* __restrict__ out_bf, int M, int N, int K)
{
    __shared__ ushort_t As[3][MT * 32];
    __shared__ ushort_t Bs[3][NT * 32];
    const int tid = threadIdx.x;
    const int w = tid >> 6, lane = tid & 63;
    constexpr int NLD = MT / 64 + NT / 64;   // glds instrs per wave per K-tile

    // XCD swizzle (bijective; m-major within each XCD chunk)
    const int gdx = gridDim.x, gdy = gridDim.y;
    const int nwg = gdx * gdy;
    const int orig = blockIdx.x + gdx * blockIdx.y;
    const int q8 = nwg >> 3, r8 = nwg & 7;
    const int xcd = orig & 7, lin = orig >> 3;
    const int wg = (xcd < r8 ? xcd * (q8 + 1) : r8 * (q8 + 1) + (xcd - r8) * q8) + lin;
    const int m0 = (wg % gdy) * MT;
    const int n0 = (wg / gdy) * NT;

    const int srow = tid >> 2;                               // 0..63
    const int scol = (((tid & 3) ^ ((srow >> 1) & 3)) * 8);  // swizzled src col
    const bf16* Agp[MT / 64];
    const bf16* Wgp[NT / 64];
    #pragma unroll
    for (int i = 0; i < MT / 64; i++)
        Agp[i] = A + (size_t)(m0 + i * 64 + srow) * K + scol;
    #pragma unroll
    for (int i = 0; i < NT / 64; i++) {
        const int nr = n0 + i * 64 + srow;
        Wgp[i] = W + (size_t)(nr < N ? nr : 0) * K + scol;
    }

    const int wy = w >> 1, wx = w & 1;
    const int fr = lane & 15;
    const int fq = lane >> 4;            // k-chunk (x8 ushorts) within K=32
    const int cxor = (fr >> 1) & 3;      // read-side swizzle (row-derived)
    constexpr int MI = MT / 32;
    constexpr int NJ = NT / 32;
    f32x4 acc[MI][NJ];
    #pragma unroll
    for (int i = 0; i < MI; i++)
        #pragma unroll
        for (int j = 0; j < NJ; j++)
            acc[i][j] = (f32x4){0.f, 0.f, 0.f, 0.f};

    const int nk = K >> 5;

    #define STAGE(buf, koff) do {                                         \
        ushort_t* sa_ = &As[buf][w * 512];                                \
        ushort_t* sb_ = &Bs[buf][w * 512];                                \
        _Pragma("unroll")                                                 \
        for (int i_ = 0; i_ < MT / 64; i_++)                              \
            glds16(Agp[i_] + (koff), sa_ + i_ * 2048);                    \
        _Pragma("unroll")                                                 \
        for (int i_ = 0; i_ < NT / 64; i_++)                              \
            glds16(Wgp[i_] + (koff), sb_ + i_ * 2048);                    \
    } while (0)

    STAGE(0, 0);
    STAGE(1, 32);
    pipe_fence<NLD>();

    int cur = 0, stg = 2;
    for (int kt = 0; kt < nk; ++kt) {
        const bool pf = (kt + 2 < nk);
        if (pf) STAGE(stg, (kt + 2) << 5);
        const ushort_t* ca = As[cur];
        const ushort_t* cb = Bs[cur];
        bf16x8 af[MI], bfv[NJ];
        #pragma unroll
        for (int i = 0; i < MI; i++) {
            const int r = wy * (MT / 2) + i * 16 + fr;
            af[i] = *(const bf16x8*)&ca[r * 32 + ((fq ^ cxor) * 8)];
        }
        #pragma unroll
        for (int j = 0; j < NJ; j++) {
            const int r = wx * (NT / 2) + j * 16 + fr;
            bfv[j] = *(const bf16x8*)&cb[r * 32 + ((fq ^ cxor) * 8)];
        }
        __builtin_amdgcn_s_setprio(1);   // T5: favor MFMA vs other blocks' staging
        #pragma unroll
        for (int i = 0; i < MI; i++)
            #pragma unroll
            for (int j = 0; j < NJ; j++)
                acc[i][j] = __builtin_amdgcn_mfma_f32_16x16x32_bf16(
                    af[i], bfv[j], acc[i][j], 0, 0, 0);
        __builtin_amdgcn_s_setprio(0);
        if (pf)               pipe_fence<NLD>();
        else if (kt + 1 < nk) pipe_fence<0>();
        cur = (cur == 2) ? 0 : cur + 1;
        stg = (stg == 2) ? 0 : stg + 1;
    }
    #undef STAGE

    // C/D layout: col = lane&15, row = (lane>>4)*4 + reg
    #pragma unroll
    for (int i = 0; i < MI; i++) {
        #pragma unroll
        for (int j = 0; j < NJ; j++) {
            const int mb = m0 + wy * (MT / 2) + i * 16 + (lane >> 4) * 4;
            const int nn = n0 + wx * (NT / 2) + j * 16 + (lane & 15);
            if (nn < N) {
                #pragma unroll
                for (int r = 0; r < 4; r++) {
                    if (EPI == 2) {
                        const float g = acc[i][j][r];
                        const float u = __shfl_xor(g, 1);
                        if (!(lane & 1)) {
                            const float a = (g / (1.f + expf(-g))) * u;
                            out_bf[(size_t)(mb + r) * INTERP + (nn >> 1)] =
                                __float2bfloat16(a);
                        }
                    } else {   // EPI == 3: split in_proj output
                        const float v = acc[i][j][r];
                        if (n0 < DINNER) {
                            Cf[(size_t)(mb + r) * DINNER + nn] = v;
                        } else if (n0 < DINNER + CONVDIM) {
                            out_bf[(size_t)(mb + r) * CONVDIM + (nn - DINNER)] =
                                __float2bfloat16(v);
                        } else {
                            aux_f[(size_t)(mb + r) * NHEADS +
                                  (nn - (DINNER + CONVDIM))] = v;
                        }
                    }
                }
            }
        }
    }
}

// ---- SMALL GEMM: 64x64 tile, NKT x 64 K-cols per barrier pair, 2-buf.
// NKT=2 for K%128==0 (16 MFMA/fence). Cf = acc + resid.
template <int NKT>
__global__ __launch_bounds__(256) void gemm_bf_s(
    const bf16* __restrict__ A, const bf16* __restrict__ W,
    float* __restrict__ Cf, const float* __restrict__ resid_f,
    int M, int N, int K)
{
    constexpr int MT = 64, NT = 64;
    __shared__ ushort_t As[2][MT * 64 * NKT];
    __shared__ ushort_t Bs[2][NT * 64 * NKT];
    const int tid = threadIdx.x;
    const int w = tid >> 6, lane = tid & 63;

    const int gdx = gridDim.x, gdy = gridDim.y;
    const int nwg = gdx * gdy;
    const int orig = blockIdx.x + gdx * blockIdx.y;
    const int q8 = nwg >> 3, r8 = nwg & 7;
    const int xcd = orig & 7, lin = orig >> 3;
    const int wg = (xcd < r8 ? xcd * (q8 + 1) : r8 * (q8 + 1) + (xcd - r8) * q8) + lin;
    const int m0 = (wg % gdy) * MT;
    const int n0 = (wg / gdy) * NT;

    const int srow = tid >> 3;                               // 0..31
    const int scol = (((tid & 7) ^ (srow & 7)) * 8);
    const bf16* Agp[2];
    const bf16* Wgp[2];
    #pragma unroll
    for (int i = 0; i < 2; i++)
        Agp[i] = A + (size_t)(m0 + i * 32 + srow) * K + scol;
    #pragma unroll
    for (int i = 0; i < 2; i++) {
        const int nr = n0 + i * 32 + srow;
        Wgp[i] = W + (size_t)(nr < N ? nr : 0) * K + scol;
    }

    const int wy = w >> 1, wx = w & 1;
    const int fr = lane & 15;
    const int fq = lane >> 4;
    f32x4 acc[2][2];
    #pragma unroll
    for (int i = 0; i < 2; i++)
        #pragma unroll
        for (int j = 0; j < 2; j++)
            acc[i][j] = (f32x4){0.f, 0.f, 0.f, 0.f};

    const int nk = K / (64 * NKT);

    #define STAGE_S(buf, koff) do {                                       \
        _Pragma("unroll")                                                 \
        for (int s_ = 0; s_ < NKT; s_++) {                                \
            _Pragma("unroll")                                             \
            for (int i_ = 0; i_ < 2; i_++) {                              \
                glds16(Agp[i_] + (koff) + s_ * 64,                        \
                       &As[buf][s_ * 4096 + i_ * 2048 + w * 512]);        \
                glds16(Wgp[i_] + (koff) + s_ * 64,                        \
                       &Bs[buf][s_ * 4096 + i_ * 2048 + w * 512]);        \
            }                                                             \
        }                                                                 \
    } while (0)

    STAGE_S(0, 0);
    __syncthreads();

    for (int kt = 0; kt < nk; ++kt) {
        const int cur = kt & 1;
        if (kt + 1 < nk) STAGE_S(cur ^ 1, (kt + 1) * (64 * NKT));
        const ushort_t* ca = As[cur];
        const ushort_t* cb = Bs[cur];
        #pragma unroll
        for (int s = 0; s < NKT; s++) {
            #pragma unroll
            for (int ks = 0; ks < 2; ks++) {
                bf16x8 af[2], bfv[2];
                #pragma unroll
                for (int i = 0; i < 2; i++) {
                    const int r = wy * 32 + i * 16 + fr;
                    const int g = ks * 4 + fq;
                    af[i] = *(const bf16x8*)&ca[s * 4096 + r * 64 + ((g ^ (r & 7)) * 8)];
                }
                #pragma unroll
                for (int j = 0; j < 2; j++) {
                    const int r = wx * 32 + j * 16 + fr;
                    const int g = ks * 4 + fq;
                    bfv[j] = *(const bf16x8*)&cb[s * 4096 + r * 64 + ((g ^ (r & 7)) * 8)];
                }
                #pragma unroll
                for (int i = 0; i < 2; i++)
                    #pragma unroll
                    for (int j = 0; j < 2; j++)
                        acc[i][j] = __builtin_amdgcn_mfma_f32_16x16x32_bf16(
                            af[i], bfv[j], acc[i][j], 0, 0, 0);
            }
        }
        __syncthreads();
    }
    #undef STAGE_S

    #pragma unroll
    for (int i = 0; i < 2; i++) {
        #pragma unroll
        for (int j = 0; j < 2; j++) {
            const int mb = m0 + wy * 32 + i * 16 + (lane >> 4) * 4;
            const int nn = n0 + wx * 32 + j * 16 + (lane & 15);
            if (nn < N) {
                #pragma unroll
                for (int r = 0; r < 4; r++) {
                    const size_t idx = (size_t)(mb + r) * N + nn;
                    Cf[idx] = acc[i][j][r] + resid_f[idx];
                }
            }
        }
    }
}

// ---- fused: depthwise causal conv (k=4)+bias+silu (4 ch/thread, bf16 in)
//      + dt = softplus(dt_raw + dt_bias) in trailing blocks (f32 dense in) ----
#define NCONVBLK ((NTOK * CONVDIM / 4) / 256)    // 4608
__global__ __launch_bounds__(256) void conv_silu_dt_kernel(
    const ushort_t* __restrict__ xbc, const float* __restrict__ dtraw,
    const float* __restrict__ cw, const float* __restrict__ cb,
    const float* __restrict__ dtbias,
    ushort_t* __restrict__ out, float* __restrict__ dtb_out)
{
    const int bid = blockIdx.x;
    if (bid < NCONVBLK) {
        const int i = bid * 256 + threadIdx.x;       // 0 .. NTOK*CONVDIM/4
        const int cg = i % (CONVDIM / 4);
        const int token = i / (CONVDIM / 4);
        const int c0 = cg * 4;
        const int l = token & (SEQLEN - 1);
        float a[4];
        #pragma unroll
        for (int j = 0; j < 4; j++) a[j] = cb[c0 + j];
        f32x4 cwv[4];
        #pragma unroll
        for (int j = 0; j < 4; j++) cwv[j] = *(const f32x4*)(cw + (c0 + j) * 4);
        #pragma unroll
        for (int k = 0; k < 4; k++) {
            const int ls = l - 3 + k;
            if (ls >= 0) {
                const u16x4 v = *(const u16x4*)(
                    xbc + (size_t)(token - 3 + k) * CONVDIM + c0);
                #pragma unroll
                for (int j = 0; j < 4; j++) a[j] += bfu2f(v[j]) * cwv[j][k];
            }
        }
        u16x4 o;
        #pragma unroll
        for (int j = 0; j < 4; j++)
            o[j] = f2bfu(a[j] / (1.f + expf(-a[j])));
        *(u16x4*)(out + (size_t)token * CONVDIM + c0) = o;
    } else {
        const int idx = (bid - NCONVBLK) * 256 + threadIdx.x;   // NTOK*NHEADS
        const int h = idx & (NHEADS - 1);
        const float v = dtraw[idx] + dtbias[h];
        dtb_out[idx] = (v > 20.f) ? v : log1pf(expf(v));
    }
}

// ================= chunked scan =================
// Phase A (MFMA): S[p,n] = sum_l (w_l x[l,p]) B[l,n],  w_l = exp(cumQ-cum_l)*dt_l
__global__ __launch_bounds__(256) void chunk_state_kernel(
    const ushort_t* __restrict__ cvb, const float* __restrict__ dtb,
    const float* __restrict__ A_log, float* __restrict__ ccum,
    ushort_t* __restrict__ Sbuf)
{
    const int bx = blockIdx.x;
    const int bh = bx >> 4, c = bx & 15;
    const int b = bh >> 5, h = bh & 31;
    const int t = threadIdx.x;
    const int w = t >> 6, lane = t & 63;
    const int wy = w >> 1, wx = w & 1;
    const int fr = lane & 15, fk = (lane >> 4) * 8, cr = (lane >> 4) * 4;
    const int tok0 = b * SEQLEN + c * Q;
    const float A = -expf(A_log[h]);

    __shared__ ushort_t sXT[64 * 88];    // [p][l], weighted
    __shared__ ushort_t sBT[128 * 88];   // [n][l]
    __shared__ float sW[64];

    if (t < 64) {
        const float d = dtb[(size_t)(tok0 + t) * NHEADS + h];
        float s = d;
        #pragma unroll
        for (int off = 1; off < 64; off <<= 1) {
            const float up = __shfl_up(s, off);
            if (t >= off) s += up;
        }
        const float total = __shfl(s, 63);
        sW[t] = expf(A * (total - s)) * d;     // arg <= 0
        if (t == 63) ccum[bh * NCHUNK + c] = A * total;
    }
    __syncthreads();

    for (int i = t; i < 64 * 64; i += 256) {
        const int l = i >> 6, p = i & 63;
        const float v = bfu2f(cvb[(size_t)(tok0 + l) * CONVDIM + h * HEADDIM + p]);
        sXT[p * 88 + l] = f2bfu(sW[l] * v);
    }
    for (int i = t; i < 128 * 64; i += 256) {
        const int l = i >> 7, n = i & 127;
        sBT[n * 88 + l] = cvb[(size_t)(tok0 + l) * CONVDIM + DINNER + n];
    }
    __syncthreads();

    f32x4 acc[2][4];
    #pragma unroll
    for (int i = 0; i < 2; i++)
        #pragma unroll
        for (int j = 0; j < 4; j++)
            acc[i][j] = (f32x4){0.f, 0.f, 0.f, 0.f};
    #pragma unroll
    for (int k0 = 0; k0 < 64; k0 += 32) {
        bf16x8 af[2], bfv[4];
        #pragma unroll
        for (int i = 0; i < 2; i++)
            af[i] = *(const bf16x8*)&sXT[(wy * 32 + i * 16 + fr) * 88 + fk + k0];
        #pragma unroll
        for (int j = 0; j < 4; j++)
            bfv[j] = *(const bf16x8*)&sBT[(wx * 64 + j * 16 + fr) * 88 + fk + k0];
        #pragma unroll
        for (int i = 0; i < 2; i++)
            #pragma unroll
            for (int j = 0; j < 4; j++)
                acc[i][j] = __builtin_amdgcn_mfma_f32_16x16x32_bf16(
                    af[i], bfv[j], acc[i][j], 0, 0, 0);
    }
    const size_t slot = (size_t)(bh * NCHUNK + c) * 64 * 128;
    #pragma unroll
    for (int i = 0; i < 2; i++) {
        #pragma unroll
        for (int j = 0; j < 4; j++) {
            #pragma unroll
            for (int r = 0; r < 4; r++) {
                const int pr = wy * 32 + i * 16 + cr + r;
                const int nn = wx * 64 + j * 16 + fr;
                Sbuf[slot + pr * 128 + nn] = f2bfu(acc[i][j][r]);
            }
        }
    }
}

// Phase B: sequential stitch; writes incoming H_c into slot c.
// 4-way split; P factors precomputed; chunk c+1's load issued BEFORE
// chunk c's store (one iteration of latency slack).
__global__ __launch_bounds__(256) void stitch_kernel(
    const float* __restrict__ ccum, ushort_t* __restrict__ Sbuf)
{
    const int bh = blockIdx.x >> 2, ng = blockIdx.x & 3;
    const int t = threadIdx.x, p = t >> 2, q = t & 3;
    float P[NCHUNK];
    #pragma unroll
    for (int c = 0; c < NCHUNK; c++) P[c] = expf(ccum[bh * NCHUNK + c]);
    float H[8];
    #pragma unroll
    for (int j = 0; j < 8; j++) H[j] = 0.f;

    const size_t off0 = (size_t)p * 128 + ng * 32 + q * 4;
    #define SLOT(c) (((size_t)(bh * NCHUNK + (c)) * 64) * 128 + off0)
    u16x4 nv0 = *(const u16x4*)&Sbuf[SLOT(0)];
    u16x4 nv1 = *(const u16x4*)&Sbuf[SLOT(0) + 16];
    for (int c = 0; c < NCHUNK; c++) {
        const u16x4 sv0 = nv0, sv1 = nv1;
        if (c + 1 < NCHUNK) {
            nv0 = *(const u16x4*)&Sbuf[SLOT(c + 1)];
            nv1 = *(const u16x4*)&Sbuf[SLOT(c + 1) + 16];
        }
        u16x4 hv0, hv1;
        #pragma unroll
        for (int k = 0; k < 4; k++) { hv0[k] = f2bfu(H[k]); hv1[k] = f2bfu(H[4 + k]); }
        *(u16x4*)&Sbuf[SLOT(c)] = hv0;
        *(u16x4*)&Sbuf[SLOT(c) + 16] = hv1;
        #pragma unroll
        for (int k = 0; k < 4; k++) {
            H[k]     = P[c] * H[k]     + bfu2f(sv0[k]);
            H[4 + k] = P[c] * H[4 + k] + bfu2f(sv1[k]);
        }
    }
    #undef SLOT
}

// Phase C (MFMA): Y = mask(C@B^T)@X + (exp(cum)*C)@H^T + D*X
// LDS diet done right: H stays in LDS but time-shares the sB region
// (sB dead after GEMM1). 8 u16x4/thread (64x128 = 2048 vectors / 256 thr)
// issue-early after GEMM1's barrier, latency hides under the exp-heavy
// sM/sC phase; ds_writes land before GEMM2's barrier.
// 71,168 -> 53,760 B LDS -> 3 blocks/CU (was 2).
__global__ __launch_bounds__(256) void chunk_scan_mfma_kernel(
    const ushort_t* __restrict__ cvb, const float* __restrict__ dtb,
    const float* __restrict__ A_log, const float* __restrict__ Dh,
    const ushort_t* __restrict__ Sbuf, bf16* __restrict__ ybuf)
{
    const int bx = blockIdx.x;
    const int bh = bx >> 4, c = bx & 15;
    const int b = bh >> 5, h = bh & 31;
    const int t = threadIdx.x;
    const int w = t >> 6, lane = t & 63;
    const int wy = w >> 1, wx = w & 1;
    const int fr = lane & 15;
    const int fk = (lane >> 4) * 8;
    const int cr = (lane >> 4) * 4;
    const int tok0 = b * SEQLEN + c * Q;
    const float A = -expf(A_log[h]);
    const float Dv = Dh[h];

    __shared__ ushort_t sB[64 * 136];    // B tile; re-used as H tile after GEMM1
    __shared__ ushort_t sC[64 * 136];
    __shared__ ushort_t sXT[64 * 72];
    __shared__ ushort_t sM[64 * 72];
    __shared__ float    sCum[64];
    __shared__ float    sDtv[64];
    ushort_t* const sH = sB;             // alias (stride 136, same region)

    for (int i = t; i < 64 * 32; i += 256) {
        const int row = i >> 5, col = (i & 31) * 4;
        const size_t base = (size_t)(tok0 + row) * CONVDIM;
        *(u16x4*)&sB[row * 136 + col] = *(const u16x4*)&cvb[base + DINNER + col];
        *(u16x4*)&sC[row * 136 + col] = *(const u16x4*)&cvb[base + DINNER + DSTATE + col];
    }
    for (int i = t; i < 64 * 32; i += 256) {
        const int p = i >> 5, l0 = (i & 31) * 2;
        const ushort_t x0 = cvb[(size_t)(tok0 + l0)     * CONVDIM + h * HEADDIM + p];
        const ushort_t x1 = cvb[(size_t)(tok0 + l0 + 1) * CONVDIM + h * HEADDIM + p];
        *(unsigned*)&sXT[p * 72 + l0] = ((unsigned)x1 << 16) | x0;
    }
    if (t < 64) {
        const float d = dtb[(size_t)(tok0 + t) * NHEADS + h];
        float s = d;
        #pragma unroll
        for (int off = 1; off < 64; off <<= 1) {
            const float up = __shfl_up(s, off);
            if (t >= off) s += up;
        }
        sCum[t] = A * s;
        sDtv[t] = d;
    }
    __syncthreads();

    // GEMM1: G = C @ B^T
    f32x4 accg[2][2];
    #pragma unroll
    for (int i = 0; i < 2; i++)
        #pragma unroll
        for (int j = 0; j < 2; j++)
            accg[i][j] = (f32x4){0.f, 0.f, 0.f, 0.f};
    #pragma unroll
    for (int k0 = 0; k0 < 128; k0 += 32) {
        bf16x8 af[2], bfv[2];
        #pragma unroll
        for (int i = 0; i < 2; i++)
            af[i] = *(const bf16x8*)&sC[(wy * 32 + i * 16 + fr) * 136 + fk + k0];
        #pragma unroll
        for (int j = 0; j < 2; j++)
            bfv[j] = *(const bf16x8*)&sB[(wx * 32 + j * 16 + fr) * 136 + fk + k0];
        #pragma unroll
        for (int i = 0; i < 2; i++)
            #pragma unroll
            for (int j = 0; j < 2; j++)
                accg[i][j] = __builtin_amdgcn_mfma_f32_16x16x32_bf16(
                    af[i], bfv[j], accg[i][j], 0, 0, 0);
    }
    __syncthreads();   // sB reads complete; region reusable as sH

    // T14 issue-early: all 8 H vectors/thread into regs (latency hides
    // under the exp-heavy sM/sC phase below)
    const size_t slot = (size_t)(bh * NCHUNK + c) * 64 * 128;
    u16x4 hr[8];
    #pragma unroll
    for (int k = 0; k < 8; k++) {
        const int i = t * 4 + k * 1024;
        hr[k] = *(const u16x4*)&Sbuf[slot + (i >> 7) * 128 + (i & 127)];
    }

    #pragma unroll
    for (int i = 0; i < 2; i++) {
        #pragma unroll
        for (int j = 0; j < 2; j++) {
            #pragma unroll
            for (int r = 0; r < 4; r++) {
                const int l  = wy * 32 + i * 16 + cr + r;
                const int jc = wx * 32 + j * 16 + fr;
                const float v = (jc <= l)
                    ? accg[i][j][r] * expf(sCum[l] - sCum[jc]) * sDtv[jc] : 0.f;
                sM[l * 72 + jc] = f2bfu(v);
            }
        }
    }
    for (int i = t; i < 64 * 32; i += 256) {
        const int row = i >> 5, col = (i & 31) * 4;
        const float sc = expf(sCum[row]);
        u16x4 v = *(const u16x4*)&sC[row * 136 + col];
        #pragma unroll
        for (int k = 0; k < 4; k++) v[k] = f2bfu(bfu2f(v[k]) * sc);
        *(u16x4*)&sC[row * 136 + col] = v;
    }
    // write-late: H into the (now dead) sB region
    #pragma unroll
    for (int k = 0; k < 8; k++) {
        const int i = t * 4 + k * 1024;
        *(u16x4*)&sH[(i >> 7) * 136 + (i & 127)] = hr[k];
    }
    __syncthreads();

    // GEMM2: Y = M @ X + (scaled C) @ H^T
    f32x4 accy[2][2];
    #pragma unroll
    for (int i = 0; i < 2; i++)
        #pragma unroll
        for (int j = 0; j < 2; j++)
            accy[i][j] = (f32x4){0.f, 0.f, 0.f, 0.f};
    #pragma unroll
    for (int k0 = 0; k0 < 64; k0 += 32) {
        bf16x8 af[2], bfv[2];
        #pragma unroll
        for (int i = 0; i < 2; i++)
            af[i] = *(const bf16x8*)&sM[(wy * 32 + i * 16 + fr) * 72 + fk + k0];
        #pragma unroll
        for (int j = 0; j < 2; j++)
            bfv[j] = *(const bf16x8*)&sXT[(wx * 32 + j * 16 + fr) * 72 + fk + k0];
        #pragma unroll
        for (int i = 0; i < 2; i++)
            #pragma unroll
            for (int j = 0; j < 2; j++)
                accy[i][j] = __builtin_amdgcn_mfma_f32_16x16x32_bf16(
                    af[i], bfv[j], accy[i][j], 0, 0, 0);
    }
    #pragma unroll
    for (int k0 = 0; k0 < 128; k0 += 32) {
        bf16x8 af[2], bfv[2];
        #pragma unroll
        for (int i = 0; i < 2; i++)
            af[i] = *(const bf16x8*)&sC[(wy * 32 + i * 16 + fr) * 136 + fk + k0];
        #pragma unroll
        for (int j = 0; j < 2; j++)
            bfv[j] = *(const bf16x8*)&sH[(wx * 32 + j * 16 + fr) * 136 + fk + k0];
        #pragma unroll
        for (int i = 0; i < 2; i++)
            #pragma unroll
            for (int j = 0; j < 2; j++)
                accy[i][j] = __builtin_amdgcn_mfma_f32_16x16x32_bf16(
                    af[i], bfv[j], accy[i][j], 0, 0, 0);
    }

    #pragma unroll
    for (int i = 0; i < 2; i++) {
        #pragma unroll
        for (int j = 0; j < 2; j++) {
            #pragma unroll
            for (int r = 0; r < 4; r++) {
                const int l = wy * 32 + i * 16 + cr + r;
                const int p = wx * 32 + j * 16 + fr;
                const float x = bfu2f(sXT[p * 72 + l]);
                ybuf[(size_t)(tok0 + l) * DINNER + h * HEADDIM + p] =
                    __float2bfloat16(accy[i][j][r] + Dv * x);
            }
        }
    }
}

// ---- ynorm = rmsnorm(y * silu(z)) over 2048 dims -> bf16 (z f32, ld DINNER) ----
__global__ __launch_bounds__(256) void gated_rmsnorm_kernel(
    const bf16* __restrict__ y, const float* __restrict__ zf,
    const float* __restrict__ w, bf16* __restrict__ out)
{
    const int token = blockIdx.x, t = threadIdx.x;
    const bf16* yr = y + (size_t)token * DINNER;
    const float* zr = zf + (size_t)token * DINNER;
    float v[8]; float ss = 0.f;
    #pragma unroll
    for (int i = 0; i < 8; i++) {
        const int idx = t * 8 + i;
        const float zz = zr[idx];
        const float val = bf2f(yr[idx]) * (zz / (1.f + expf(-zz)));
        v[i] = val; ss += val * val;
    }
    ss = block_reduce_sum(ss);
    const float scale = rsqrtf(ss * (1.0f / DINNER) + 1e-6f);
    #pragma unroll
    for (int i = 0; i < 8; i++) {
        const int idx = t * 8 + i;
        out[(size_t)token * DINNER + idx] =
            __float2bfloat16(v[i] * scale * w[idx]);
    }
}

extern "C" void kernel_launch(void* const* d_in, const int* in_sizes, int n_in,
                              void* d_out, int out_size, void* d_ws, size_t ws_size,
                              hipStream_t stream) {
    const float* hidden     = (const float*)d_in[0];
    const float* norm_w     = (const float*)d_in[1];
    const float* in_proj_w  = (const float*)d_in[2];
    const float* conv_w     = (const float*)d_in[3];
    const float* conv_b     = (const float*)d_in[4];
    const float* dt_bias    = (const float*)d_in[5];
    const float* A_log      = (const float*)d_in[6];
    const float* Dh         = (const float*)d_in[7];
    const float* ssm_norm_w = (const float*)d_in[8];
    const float* out_proj_w = (const float*)d_in[9];
    const float* post_norm_w= (const float*)d_in[10];
    const float* gate_w     = (const float*)d_in[11];
    const float* up_w       = (const float*)d_in[12];
    const float* down_w     = (const float*)d_in[13];
    float* out = (float*)d_out;

    // ---- workspace layout (fl units) ----
    float* ws = (float*)d_ws;
    bf16*  h_norm = (bf16*)(ws);                 // [0, 1,048,576)
    float* zf     = ws + 1048576;                // f32 z 2048x2048 -> [.., 5,242,880)
    ushort_t* xbc = (ushort_t*)(ws + 5242880);   // bf16 2048x2304 -> [.., 7,602,176)
    float* dtraw  = ws + 7602176;                // f32 2048x32    -> [.., 7,667,712)
    ushort_t* cvb = (ushort_t*)(ws + 10027008);  // bf16 2048x2304
    float* dtb    = ws + 14745600;               // [14,745,600, 14,811,136)
    float* ccum   = ws + 14811136;               // 1024 fl
    ushort_t* Sbuf= (ushort_t*)(ws + 14812160);  // [14,812,160, 19,006,464) bf16
    float* xbuf   = ws + 19006464;               // [19,006,464, 21,103,616)
    bf16*  ybuf   = (bf16*)(ws + 21103616);      // [21,103,616, 22,152,192)
    bf16*  ynorm  = (bf16*)(ws + 22152192);      // [22,152,192, 23,200,768)
    // just-in-time bf16 weights in dead regions (zf/xbc dead after step 6):
    ushort_t* Wip = (ushort_t*)(ws + 10027008);  // cvb region, dead before conv
    ushort_t* Wop = (ushort_t*)(ws + 1048576);   // over zf (dead after step 6)
    ushort_t* Wgu = (ushort_t*)(ws + 2097152);   // interleaved gate/up
    ushort_t* Wdn = (ushort_t*)(ws + 4915200);   // 1024x2816 -> [.., 6,356,992)
    bf16*  act    = (bf16*)(ws + 6356992);       // 2048x2816 -> [.., 9,240,576)
    bf16*  h2     = h_norm;                      // reuse

    // 0+1. fused: h = rmsnorm(hidden) -> bf16  AND  Wip = bf16(in_proj_w)
    prep_kernel<<<NTOK + 4384, 256, 0, stream>>>(hidden, norm_w, h_norm,
                                                 in_proj_w, Wip);
    // 2. zxbcdt = h @ Wip^T, split output: z f32 / xBC bf16 / dt_raw f32
    gemm_bf<3, 128, 128><<<dim3(35, 16), 256, 0, stream>>>(h_norm, (const bf16*)Wip,
        zf, dtraw, (bf16*)xbc, NTOK, DINPROJ, DMODEL);
    // 3+4. conv(k=4)+bias+silu (bf16 in, vectorized x4) fused with dt softplus
    conv_silu_dt_kernel<<<NCONVBLK + (NTOK * NHEADS) / 256, 256, 0, stream>>>(
        xbc, dtraw, conv_w, conv_b, dt_bias, cvb, dtb);
    // 5. chunked selective scan -> ybuf (bf16)
    chunk_state_kernel<<<1024, 256, 0, stream>>>(cvb, dtb, A_log, ccum, Sbuf);
    stitch_kernel<<<256, 256, 0, stream>>>(ccum, Sbuf);
    chunk_scan_mfma_kernel<<<1024, 256, 0, stream>>>(cvb, dtb, A_log, Dh, Sbuf, ybuf);
    // 6. ynorm = rmsnorm(y * silu(z), ssm_norm_w)  -> bf16 (last use of zf)
    gated_rmsnorm_kernel<<<NTOK, 256, 0, stream>>>(ybuf, zf, ssm_norm_w, ynorm);
    // 6b. convert out_proj/gate+up(interleaved)/down(ld 2816) + zero K-pads
    convert_weights_kernel<<<(NWOP + 3 * NWG + WDN_PAD + ACT_PAD) / 1024, 256, 0,
        stream>>>(out_proj_w, gate_w, up_w, down_w, Wop, Wgu, Wdn, (ushort_t*)act);
    // 7. x = hidden + ynorm @ Wop^T  (f32), 64x64 NKT=2 (K=2048) -> 512 blocks
    gemm_bf_s<2><<<dim3(16, 32), 256, 0, stream>>>(ynorm, (const bf16*)Wop, xbuf,
        hidden, NTOK, DMODEL, DINNER);
    // 8. h2 = rmsnorm(x, post_norm_w)  -> bf16
    rmsnorm1024_kernel<<<NTOK, 256, 0, stream>>>(xbuf, post_norm_w, h2);
    // 9+10. act = swiglu(h2 @ Wgu^T)  (fused epilogue, act ld = 2816)
    gemm_bf<2, 128, 128><<<dim3(43, 16), 256, 0, stream>>>(h2, (const bf16*)Wgu,
        nullptr, nullptr, act, NTOK, 2 * INTER, DMODEL);
    // 11. out = x + act @ Wdn^T  (f32 to d_out), 64x64 NKT=2 (K=2816, zero pad)
    gemm_bf_s<2><<<dim3(16, 32), 256, 0, stream>>>(act, (const bf16*)Wdn, out,
        xbuf, NTOK, DMODEL, INTERP);
}